// Round 1
// baseline (313.661 us; speedup 1.0000x reference)
//
#include <hip/hip_runtime.h>
#include <stdint.h>
#include <math.h>

// ProductMonoidHead — f32 baseline, round 1.
// B=8 N=M=1024 D=1024 MB=32 H=128.
// d_out = out[8,1024,128] (1048576 f32) ++ attn[8,1024,1024] (8388608 f32).
// ws: Qt,Qr,Kt,Kr [8192][32] | Vp [8192][128] | Qbits,Kbits u32[8192] | P [4][8192][128]
// attn region doubles as scratch for Q/K projection partials before scores overwrite it.

#define SCALE_F 0.17677669529663687f

typedef float4 f4;

__device__ __forceinline__ float f4c(const f4 v, int i) {
    return i == 0 ? v.x : (i == 1 ? v.y : (i == 2 ? v.z : v.w));
}

// ---------------- projections: X[8192,1024] @ W[1024,cols], d-split x4 partials ----------------

__global__ __launch_bounds__(256)
void proj_qk_kernel(const float* __restrict__ Q, const float* __restrict__ K,
                    const float* __restrict__ Wqb, const float* __restrict__ Wkb,
                    const float* __restrict__ Wqt, const float* __restrict__ Wkt,
                    const float* __restrict__ Wqr, const float* __restrict__ Wkr,
                    float* __restrict__ Pq, float* __restrict__ Pk) {
    const int t = threadIdx.x;
    const int bx = blockIdx.x;          // 64 row blocks (128 rows each)
    const int by = blockIdx.y;          // 4 d-splits (256 d each)
    const int side = blockIdx.z;        // 0=Q, 1=K
    const float* __restrict__ X  = side ? K   : Q;
    const float* __restrict__ Wb = side ? Wkb : Wqb;
    const float* __restrict__ Wt = side ? Wkt : Wqt;
    const float* __restrict__ Wr = side ? Wkr : Wqr;
    float* __restrict__ P = side ? Pk : Pq;

    __shared__ float Xs[128][68];       // +4 pad: breaks pow2 bank stride
    __shared__ float Ws[64][96];        // cols 0-31 bool | 32-63 trop | 64-95 real

    const int r0 = bx * 128;
    const int rt = t >> 3;              // 0..31 -> 4 rows each
    const int cg = t & 7;               // 0..7  -> cols 12*cg..12*cg+11

    float acc[4][12];
    #pragma unroll
    for (int i = 0; i < 4; ++i)
        #pragma unroll
        for (int j = 0; j < 12; ++j) acc[i][j] = 0.f;

    for (int dc = 0; dc < 4; ++dc) {
        const int dbase = by * 256 + dc * 64;
        #pragma unroll
        for (int k2 = 0; k2 < 8; ++k2) {          // X tile: 128x64 = 2048 f4
            int idx = t + k2 * 256;
            int r = idx >> 4, c4 = idx & 15;
            *(f4*)&Xs[r][c4 * 4] = *(const f4*)&X[(size_t)(r0 + r) * 1024 + dbase + c4 * 4];
        }
        #pragma unroll
        for (int k2 = 0; k2 < 6; ++k2) {          // W tile: 64x96 = 1536 f4
            int idx = t + k2 * 256;
            int d = idx / 24, c4 = idx % 24;
            const float* __restrict__ src = (c4 < 8) ? Wb : ((c4 < 16) ? Wt : Wr);
            *(f4*)&Ws[d][c4 * 4] = *(const f4*)&src[(size_t)(dbase + d) * 32 + (c4 & 7) * 4];
        }
        __syncthreads();
        for (int dd = 0; dd < 64; dd += 4) {
            f4 xf[4];
            #pragma unroll
            for (int i = 0; i < 4; ++i) xf[i] = *(const f4*)&Xs[4 * rt + i][dd];
            #pragma unroll
            for (int d2 = 0; d2 < 4; ++d2) {
                f4 wf[3];
                #pragma unroll
                for (int jj = 0; jj < 3; ++jj)
                    wf[jj] = *(const f4*)&Ws[dd + d2][12 * cg + 4 * jj];
                #pragma unroll
                for (int i = 0; i < 4; ++i) {
                    const float xv = f4c(xf[i], d2);
                    #pragma unroll
                    for (int jj = 0; jj < 3; ++jj) {
                        acc[i][jj * 4 + 0] += xv * wf[jj].x;
                        acc[i][jj * 4 + 1] += xv * wf[jj].y;
                        acc[i][jj * 4 + 2] += xv * wf[jj].z;
                        acc[i][jj * 4 + 3] += xv * wf[jj].w;
                    }
                }
            }
        }
        __syncthreads();
    }
    #pragma unroll
    for (int i = 0; i < 4; ++i) {
        size_t base = ((size_t)by * 8192 + r0 + 4 * rt + i) * 96 + 12 * cg;
        *(f4*)&P[base + 0] = make_float4(acc[i][0], acc[i][1], acc[i][2],  acc[i][3]);
        *(f4*)&P[base + 4] = make_float4(acc[i][4], acc[i][5], acc[i][6],  acc[i][7]);
        *(f4*)&P[base + 8] = make_float4(acc[i][8], acc[i][9], acc[i][10], acc[i][11]);
    }
}

__global__ __launch_bounds__(256)
void proj_v_kernel(const float* __restrict__ V, const float* __restrict__ Wv,
                   float* __restrict__ P) {
    const int t = threadIdx.x;
    const int r0 = blockIdx.x * 128;
    const int by = blockIdx.y;          // 4 d-splits
    __shared__ float Xs[128][36];
    __shared__ float Ws[32][128];
    const int rt = t >> 3, cg = t & 7;  // 4 rows x 16 cols per thread

    float acc[4][16];
    #pragma unroll
    for (int i = 0; i < 4; ++i)
        #pragma unroll
        for (int j = 0; j < 16; ++j) acc[i][j] = 0.f;

    for (int dc = 0; dc < 8; ++dc) {
        const int dbase = by * 256 + dc * 32;
        #pragma unroll
        for (int k2 = 0; k2 < 4; ++k2) {          // X tile: 128x32 = 1024 f4
            int idx = t + k2 * 256;
            int r = idx >> 3, c4 = idx & 7;
            *(f4*)&Xs[r][c4 * 4] = *(const f4*)&V[(size_t)(r0 + r) * 1024 + dbase + c4 * 4];
        }
        #pragma unroll
        for (int k2 = 0; k2 < 4; ++k2) {          // W tile: 32x128 = 1024 f4
            int idx = t + k2 * 256;
            int d = idx >> 5, c4 = idx & 31;
            *(f4*)&Ws[d][c4 * 4] = *(const f4*)&Wv[(size_t)(dbase + d) * 128 + c4 * 4];
        }
        __syncthreads();
        for (int dd = 0; dd < 32; dd += 4) {
            f4 xf[4];
            #pragma unroll
            for (int i = 0; i < 4; ++i) xf[i] = *(const f4*)&Xs[4 * rt + i][dd];
            #pragma unroll
            for (int d2 = 0; d2 < 4; ++d2) {
                f4 wf[4];
                #pragma unroll
                for (int jj = 0; jj < 4; ++jj)
                    wf[jj] = *(const f4*)&Ws[dd + d2][16 * cg + 4 * jj];
                #pragma unroll
                for (int i = 0; i < 4; ++i) {
                    const float xv = f4c(xf[i], d2);
                    #pragma unroll
                    for (int jj = 0; jj < 4; ++jj) {
                        acc[i][jj * 4 + 0] += xv * wf[jj].x;
                        acc[i][jj * 4 + 1] += xv * wf[jj].y;
                        acc[i][jj * 4 + 2] += xv * wf[jj].z;
                        acc[i][jj * 4 + 3] += xv * wf[jj].w;
                    }
                }
            }
        }
        __syncthreads();
    }
    #pragma unroll
    for (int i = 0; i < 4; ++i) {
        size_t base = ((size_t)by * 8192 + r0 + 4 * rt + i) * 128 + 16 * cg;
        #pragma unroll
        for (int jj = 0; jj < 4; ++jj)
            *(f4*)&P[base + 4 * jj] = make_float4(acc[i][jj * 4 + 0], acc[i][jj * 4 + 1],
                                                  acc[i][jj * 4 + 2], acc[i][jj * 4 + 3]);
    }
}

// ---------------- pack: sum d-split partials -> codes + sign bits ----------------

__global__ __launch_bounds__(256)
void pack_codes_kernel(const float* __restrict__ Pq, const float* __restrict__ Pk,
                       float* __restrict__ Qt, float* __restrict__ Qr,
                       float* __restrict__ Kt, float* __restrict__ Kr) {
    const int gid = blockIdx.x * 256 + threadIdx.x;    // 524288 per side
    const int side = blockIdx.y;
    const float* __restrict__ P = side ? Pk : Pq;
    const int row = gid >> 6, c = gid & 63;            // cols 32..95 of partials
    float s = 0.f;
    #pragma unroll
    for (int g = 0; g < 4; ++g) s += P[((size_t)g * 8192 + row) * 96 + 32 + c];
    float* __restrict__ dT = side ? Kt : Qt;
    float* __restrict__ dR = side ? Kr : Qr;
    if (c < 32) dT[row * 32 + c] = s;
    else        dR[row * 32 + (c - 32)] = s;
}

__global__ __launch_bounds__(256)
void pack_bits_kernel(const float* __restrict__ Pq, const float* __restrict__ Pk,
                      uint32_t* __restrict__ Qbits, uint32_t* __restrict__ Kbits) {
    const int gid = blockIdx.x * 256 + threadIdx.x;    // 262144 per side
    const int side = blockIdx.y;
    const float* __restrict__ P = side ? Pk : Pq;
    const int row = gid >> 5, c = gid & 31;            // bool cols 0..31
    float s = 0.f;
    #pragma unroll
    for (int g = 0; g < 4; ++g) s += P[((size_t)g * 8192 + row) * 96 + c];
    const unsigned long long bm = __ballot(s > 0.f);   // wave64 -> 2 rows per wave
    uint32_t* __restrict__ bits = side ? Kbits : Qbits;
    const int lane = threadIdx.x & 63;
    if (lane == 0)       bits[row] = (uint32_t)bm;
    else if (lane == 32) bits[row] = (uint32_t)(bm >> 32);
}

__global__ __launch_bounds__(256)
void reduce4_kernel(const float* __restrict__ P, float* __restrict__ dst) {
    const int gid = blockIdx.x * 256 + threadIdx.x;    // 262144 f4
    f4 a = ((const f4*)P)[gid];
    f4 b = ((const f4*)P)[262144 + gid];
    f4 c = ((const f4*)P)[2 * 262144 + gid];
    f4 d = ((const f4*)P)[3 * 262144 + gid];
    ((f4*)dst)[gid] = make_float4(a.x + b.x + c.x + d.x, a.y + b.y + c.y + d.y,
                                  a.z + b.z + c.z + d.z, a.w + b.w + c.w + d.w);
}

// ---------------- fused sims -> raw scores (64n x 64m tiles) ----------------

__global__ __launch_bounds__(256)
void scores_kernel(const float* __restrict__ Qt, const float* __restrict__ Qr,
                   const float* __restrict__ Kt, const float* __restrict__ Kr,
                   const uint32_t* __restrict__ Qbits, const uint32_t* __restrict__ Kbits,
                   const float* __restrict__ fw, float* __restrict__ attn) {
    const int t = threadIdx.x;
    const int m0 = blockIdx.x * 64;
    const int n0 = blockIdx.y * 64;
    const int b  = blockIdx.z;

    __shared__ float Qt_s[64][36], Qr_s[64][36];       // row-major, pad 36
    __shared__ float KtT[32][68],  KrT[32][68];        // d-major (transposed), pad 68
    __shared__ uint32_t qb_s[64], kb_s[64];

    #pragma unroll
    for (int k2 = 0; k2 < 2; ++k2) {
        int idx = t + k2 * 256;                        // 512 = 64 rows x 8 f4
        int r = idx >> 3, c4 = idx & 7;
        *(f4*)&Qt_s[r][c4 * 4] = *(const f4*)&Qt[(size_t)(b * 1024 + n0 + r) * 32 + c4 * 4];
        *(f4*)&Qr_s[r][c4 * 4] = *(const f4*)&Qr[(size_t)(b * 1024 + n0 + r) * 32 + c4 * 4];
        f4 vt = *(const f4*)&Kt[(size_t)(b * 1024 + m0 + r) * 32 + c4 * 4];
        f4 vr = *(const f4*)&Kr[(size_t)(b * 1024 + m0 + r) * 32 + c4 * 4];
        KtT[c4 * 4 + 0][r] = vt.x; KtT[c4 * 4 + 1][r] = vt.y;
        KtT[c4 * 4 + 2][r] = vt.z; KtT[c4 * 4 + 3][r] = vt.w;
        KrT[c4 * 4 + 0][r] = vr.x; KrT[c4 * 4 + 1][r] = vr.y;
        KrT[c4 * 4 + 2][r] = vr.z; KrT[c4 * 4 + 3][r] = vr.w;
    }
    if (t < 64)       qb_s[t] = Qbits[b * 1024 + n0 + t];
    else if (t < 128) kb_s[t - 64] = Kbits[b * 1024 + m0 + (t - 64)];
    __syncthreads();

    // fusion softmax weights (fw==ones -> exactly 1/3 each)
    const float f0 = fw[0], f1 = fw[1], f2 = fw[2];
    const float fm = fmaxf(f0, fmaxf(f1, f2));
    const float e0 = __expf(f0 - fm), e1 = __expf(f1 - fm), e2 = __expf(f2 - fm);
    const float wi = 1.f / (e0 + e1 + e2);
    const float w0 = e0 * wi, w1 = e1 * wi, w2 = e2 * wi;

    const int rg = t >> 4, mg = t & 15;                // 4x4 micro-tile

    float tacc[4][4], racc[4][4];
    #pragma unroll
    for (int i = 0; i < 4; ++i)
        #pragma unroll
        for (int j = 0; j < 4; ++j) { tacc[i][j] = -INFINITY; racc[i][j] = 0.f; }

    for (int d0 = 0; d0 < 32; d0 += 4) {
        f4 qt4[4], qr4[4];
        #pragma unroll
        for (int i = 0; i < 4; ++i) {
            qt4[i] = *(const f4*)&Qt_s[4 * rg + i][d0];
            qr4[i] = *(const f4*)&Qr_s[4 * rg + i][d0];
        }
        #pragma unroll
        for (int d2 = 0; d2 < 4; ++d2) {
            const f4 kt = *(const f4*)&KtT[d0 + d2][4 * mg];
            const f4 kr = *(const f4*)&KrT[d0 + d2][4 * mg];
            #pragma unroll
            for (int i = 0; i < 4; ++i) {
                const float qtv = f4c(qt4[i], d2);
                const float qrv = f4c(qr4[i], d2);
                tacc[i][0] = fmaxf(tacc[i][0], qtv + kt.x);
                tacc[i][1] = fmaxf(tacc[i][1], qtv + kt.y);
                tacc[i][2] = fmaxf(tacc[i][2], qtv + kt.z);
                tacc[i][3] = fmaxf(tacc[i][3], qtv + kt.w);
                racc[i][0] += qrv * kr.x;
                racc[i][1] += qrv * kr.y;
                racc[i][2] += qrv * kr.z;
                racc[i][3] += qrv * kr.w;
            }
        }
    }

    uint32_t qb[4], kb[4];
    #pragma unroll
    for (int i = 0; i < 4; ++i) { qb[i] = qb_s[4 * rg + i]; kb[i] = kb_s[4 * mg + i]; }
    #pragma unroll
    for (int i = 0; i < 4; ++i) {
        float sj[4];
        #pragma unroll
        for (int j = 0; j < 4; ++j) {
            const float cnt = (float)(32 - __popc(qb[i] ^ kb[j]));
            sj[j] = (w0 * cnt + w1 * tacc[i][j] + w2 * racc[i][j]) * SCALE_F;
        }
        *(f4*)&attn[(size_t)(b * 1024 + n0 + 4 * rg + i) * 1024 + m0 + 4 * mg] =
            make_float4(sj[0], sj[1], sj[2], sj[3]);
    }
}

// ---------------- per-row masked softmax (in place on attn) ----------------

__global__ __launch_bounds__(256)
void softmax_kernel(float* __restrict__ attn, const int* __restrict__ mask) {
    const int row = blockIdx.x;                        // 8192 rows
    const int t = threadIdx.x;
    const f4  s4 = ((const f4*)attn)[(size_t)row * 256 + t];
    const int4 m4 = ((const int4*)mask)[(size_t)row * 256 + t];
    const float v0 = m4.x ? s4.x : -INFINITY;
    const float v1 = m4.y ? s4.y : -INFINITY;
    const float v2 = m4.z ? s4.z : -INFINITY;
    const float v3 = m4.w ? s4.w : -INFINITY;

    float tm = fmaxf(fmaxf(v0, v1), fmaxf(v2, v3));
    #pragma unroll
    for (int off = 32; off >= 1; off >>= 1) tm = fmaxf(tm, __shfl_xor(tm, off, 64));
    __shared__ float rmax[4], rsum[4];
    if ((t & 63) == 0) rmax[t >> 6] = tm;
    __syncthreads();
    const float gm = fmaxf(fmaxf(rmax[0], rmax[1]), fmaxf(rmax[2], rmax[3]));

    const float x0 = m4.x ? __expf(v0 - gm) : 0.f;
    const float x1 = m4.y ? __expf(v1 - gm) : 0.f;
    const float x2 = m4.z ? __expf(v2 - gm) : 0.f;
    const float x3 = m4.w ? __expf(v3 - gm) : 0.f;
    float ts = (x0 + x1) + (x2 + x3);
    #pragma unroll
    for (int off = 32; off >= 1; off >>= 1) ts += __shfl_xor(ts, off, 64);
    if ((t & 63) == 0) rsum[t >> 6] = ts;
    __syncthreads();
    const float inv = 1.f / (((rsum[0] + rsum[1]) + (rsum[2] + rsum[3])));

    ((f4*)attn)[(size_t)row * 256 + t] = make_float4(x0 * inv, x1 * inv, x2 * inv, x3 * inv);
}

// ---------------- PV: out = attn @ Vp, m-split x4 partials ----------------

__global__ __launch_bounds__(256)
void pv_kernel(const float* __restrict__ attn, const float* __restrict__ Vp,
               float* __restrict__ Pout) {
    const int t = threadIdx.x;
    const int row0 = blockIdx.x * 64;                  // over 8192 global rows
    const int ms = blockIdx.y;                         // 4 m-splits of 256
    const int b = row0 >> 10;
    __shared__ float As[64][68];
    __shared__ float Vs[64][128];
    const int rt = t >> 4, hg = t & 15;                // 4 rows x 8 h per thread

    float acc[4][8];
    #pragma unroll
    for (int i = 0; i < 4; ++i)
        #pragma unroll
        for (int j = 0; j < 8; ++j) acc[i][j] = 0.f;

    for (int mc = 0; mc < 4; ++mc) {
        const int mb = ms * 256 + mc * 64;
        #pragma unroll
        for (int k2 = 0; k2 < 4; ++k2) {               // attn tile 64x64 = 1024 f4
            int idx = t + k2 * 256;
            int r = idx >> 4, c4 = idx & 15;
            *(f4*)&As[r][c4 * 4] = *(const f4*)&attn[(size_t)(row0 + r) * 1024 + mb + c4 * 4];
        }
        #pragma unroll
        for (int k2 = 0; k2 < 8; ++k2) {               // V tile 64x128 = 2048 f4
            int idx = t + k2 * 256;
            int m = idx >> 5, c4 = idx & 31;
            *(f4*)&Vs[m][c4 * 4] = *(const f4*)&Vp[(size_t)(b * 1024 + mb + m) * 128 + c4 * 4];
        }
        __syncthreads();
        for (int m = 0; m < 64; ++m) {
            const f4 u0 = *(const f4*)&Vs[m][hg * 8];
            const f4 u1 = *(const f4*)&Vs[m][hg * 8 + 4];
            #pragma unroll
            for (int i = 0; i < 4; ++i) {
                const float a = As[4 * rt + i][m];
                acc[i][0] += a * u0.x; acc[i][1] += a * u0.y;
                acc[i][2] += a * u0.z; acc[i][3] += a * u0.w;
                acc[i][4] += a * u1.x; acc[i][5] += a * u1.y;
                acc[i][6] += a * u1.z; acc[i][7] += a * u1.w;
            }
        }
        __syncthreads();
    }
    #pragma unroll
    for (int i = 0; i < 4; ++i) {
        size_t base = ((size_t)ms * 8192 + row0 + 4 * rt + i) * 128 + hg * 8;
        *(f4*)&Pout[base]     = make_float4(acc[i][0], acc[i][1], acc[i][2], acc[i][3]);
        *(f4*)&Pout[base + 4] = make_float4(acc[i][4], acc[i][5], acc[i][6], acc[i][7]);
    }
}

// ---------------- launch ----------------

extern "C" void kernel_launch(void* const* d_in, const int* in_sizes, int n_in,
                              void* d_out, int out_size, void* d_ws, size_t ws_size,
                              hipStream_t stream) {
    const float* Q   = (const float*)d_in[0];
    const float* K   = (const float*)d_in[1];
    const float* V   = (const float*)d_in[2];
    const float* Wqb = (const float*)d_in[3];
    const float* Wkb = (const float*)d_in[4];
    const float* Wqt = (const float*)d_in[5];
    const float* Wkt = (const float*)d_in[6];
    const float* Wqr = (const float*)d_in[7];
    const float* Wkr = (const float*)d_in[8];
    const float* Wv  = (const float*)d_in[9];
    const float* fw  = (const float*)d_in[10];
    const int*  mask = (const int*)d_in[11];

    float* ws = (float*)d_ws;
    float* Qt = ws;                       // [8192][32]
    float* Qr = Qt + 262144;
    float* Kt = Qr + 262144;
    float* Kr = Kt + 262144;
    float* Vp = Kr + 262144;              // [8192][128]
    uint32_t* Qbits = (uint32_t*)(Vp + 1048576);   // [8192]
    uint32_t* Kbits = Qbits + 8192;
    float* Pbig = (float*)(Kbits + 8192); // [4][8192][128]  (Vp partials, then PV partials)

    float* out  = (float*)d_out;          // [8192][128]
    float* attn = out + 1048576;          // [8192][1024]
    float* Pq = attn;                     // [4][8192][96] proj partials (scratch before scores)
    float* Pk = attn + 3145728;

    proj_qk_kernel<<<dim3(64, 4, 2), 256, 0, stream>>>(Q, K, Wqb, Wkb, Wqt, Wkt, Wqr, Wkr, Pq, Pk);
    proj_v_kernel<<<dim3(64, 4), 256, 0, stream>>>(V, Wv, Pbig);
    pack_codes_kernel<<<dim3(2048, 2), 256, 0, stream>>>(Pq, Pk, Qt, Qr, Kt, Kr);
    pack_bits_kernel<<<dim3(1024, 2), 256, 0, stream>>>(Pq, Pk, Qbits, Kbits);
    reduce4_kernel<<<1024, 256, 0, stream>>>(Pbig, Vp);
    scores_kernel<<<dim3(16, 16, 8), 256, 0, stream>>>(Qt, Qr, Kt, Kr, Qbits, Kbits, fw, attn);
    softmax_kernel<<<8192, 256, 0, stream>>>(attn, mask);
    pv_kernel<<<dim3(128, 4), 256, 0, stream>>>(attn, Vp, Pbig);
    reduce4_kernel<<<1024, 256, 0, stream>>>(Pbig, out);
}

// Round 2
// 284.835 us; speedup vs baseline: 1.1012x; 1.1012x over previous
//
#include <hip/hip_runtime.h>
#include <stdint.h>
#include <math.h>

// ProductMonoidHead — round 2: MFMA bf16 compensated GEMMs.
// B=8 N=M=1024 D=1024 MB=32 H=128.
// d_out = out[8192][128] f32 ++ attn[8192][1024] f32.
// Numerics: projections use bf16 hi/mid(/lo3) splits:
//   trop/real/V/PV: 3-term (h*h + h*m + m*h), err ~4e-6 (f32-like for continuous paths)
//   bool sign path: 3-way split, 6 terms (h h, h m, m h, m m, h l, l h), err ~2e-6
//     => sign-flip probability vs f32 reference ~ baseline level.

#define SCALE_F 0.17677669529663687f

typedef float4 f4;
typedef __attribute__((ext_vector_type(8))) short s16x8;
typedef __attribute__((ext_vector_type(8))) unsigned short u16x8;
typedef __attribute__((ext_vector_type(4))) float f32x4;

__device__ __forceinline__ unsigned short f2bf(float x) {
    unsigned u = __float_as_uint(x);
    return (unsigned short)((u + 0x7FFFu + ((u >> 16) & 1u)) >> 16);
}
__device__ __forceinline__ float bf2f(unsigned short h) {
    return __uint_as_float(((unsigned)h) << 16);
}
__device__ __forceinline__ float f4c(const f4 v, int i) {
    return i == 0 ? v.x : (i == 1 ? v.y : (i == 2 ? v.z : v.w));
}

#define MFMA16(a, b, c) __builtin_amdgcn_mfma_f32_16x16x32_bf16((a), (b), (c), 0, 0, 0)

// ---------------- conv_w: build transposed bf16 W images ----------------
// Wh/Wm: [side*96+col][1024]  (col 0-31 bool, 32-63 trop, 64-95 real)
// Wl3:   [side*32+col][1024]  (bool 3rd level)
// Wvh/Wvm: [h=128][1024]

__global__ __launch_bounds__(256)
void conv_w_kernel(const float* __restrict__ Wqb, const float* __restrict__ Wkb,
                   const float* __restrict__ Wqt, const float* __restrict__ Wkt,
                   const float* __restrict__ Wqr, const float* __restrict__ Wkr,
                   const float* __restrict__ Wv,
                   unsigned short* __restrict__ Wh, unsigned short* __restrict__ Wm,
                   unsigned short* __restrict__ Wl3,
                   unsigned short* __restrict__ Wvh, unsigned short* __restrict__ Wvm) {
    __shared__ float T[256][33];
    const int t = threadIdx.x;
    const int bid = blockIdx.x;
    const float* src;
    int kb, outRowBase, srcStride, srcColBase, side = 0;
    bool isQK, isBool;
    if (bid < 24) {
        side = bid / 12;
        int cb = (bid % 12) / 4;
        kb = bid & 3;
        const float* mats[6] = {Wqb, Wqt, Wqr, Wkb, Wkt, Wkr};
        src = mats[side * 3 + cb];
        srcStride = 32; srcColBase = 0;
        outRowBase = side * 96 + cb * 32;
        isQK = true; isBool = (cb == 0);
    } else {
        int v = bid - 24;
        int hb = v >> 2; kb = v & 3;
        src = Wv; srcStride = 128; srcColBase = hb * 32;
        outRowBase = hb * 32;
        isQK = false; isBool = false;
    }
    #pragma unroll
    for (int i = 0; i < 8; ++i) {
        int idx = t + i * 256;
        int r = idx >> 3, c4 = idx & 7;
        f4 v = *(const f4*)&src[(size_t)(kb * 256 + r) * srcStride + srcColBase + c4 * 4];
        T[r][c4 * 4 + 0] = v.x; T[r][c4 * 4 + 1] = v.y;
        T[r][c4 * 4 + 2] = v.z; T[r][c4 * 4 + 3] = v.w;
    }
    __syncthreads();
    const int col = t >> 3, kseg = t & 7;
    unsigned short* dh = isQK ? Wh : Wvh;
    unsigned short* dm = isQK ? Wm : Wvm;
    size_t obase = (size_t)(outRowBase + col) * 1024 + kb * 256 + kseg * 32;
    u16x8 ph[4], pm[4], pl[4];
    #pragma unroll
    for (int i = 0; i < 32; ++i) {
        float x = T[kseg * 32 + i][col];
        unsigned short hb_ = f2bf(x);
        float r1 = x - bf2f(hb_);
        unsigned short mb_ = f2bf(r1);
        float r2 = r1 - bf2f(mb_);
        ph[i >> 3][i & 7] = hb_;
        pm[i >> 3][i & 7] = mb_;
        pl[i >> 3][i & 7] = f2bf(r2);
    }
    #pragma unroll
    for (int i = 0; i < 4; ++i) {
        *(u16x8*)&dh[obase + i * 8] = ph[i];
        *(u16x8*)&dm[obase + i * 8] = pm[i];
    }
    if (isBool) {
        size_t lbase = (size_t)(side * 32 + col) * 1024 + kb * 256 + kseg * 32;
        #pragma unroll
        for (int i = 0; i < 4; ++i) *(u16x8*)&Wl3[lbase + i * 8] = pl[i];
    }
}

// ---------------- proj_qk: MFMA, 32-row tiles, emits codes + sign bits ----------------

__global__ __launch_bounds__(256)
void proj_qk_kernel(const float* __restrict__ Q, const float* __restrict__ K,
                    const unsigned short* __restrict__ Wh, const unsigned short* __restrict__ Wm,
                    const unsigned short* __restrict__ Wl3,
                    float* __restrict__ Qt, float* __restrict__ Qr,
                    float* __restrict__ Kt, float* __restrict__ Kr,
                    unsigned* __restrict__ Qbits, unsigned* __restrict__ Kbits) {
    const int t = threadIdx.x, lane = t & 63, w = t >> 6;
    const int side = blockIdx.y;
    const int gr0 = blockIdx.x * 32;
    const float* __restrict__ X = side ? K : Q;
    float* __restrict__ Tt = side ? Kt : Qt;
    float* __restrict__ Tr = side ? Kr : Qr;
    unsigned* __restrict__ Tb = side ? Kbits : Qbits;

    __shared__ unsigned short Ah[2][1024], Am[2][1024], Al[2][1024];
    __shared__ unsigned short BhS[2][3072], BmS[2][3072], BlS[2][1024];
    __shared__ unsigned sb[32];
    if (t < 32) sb[t] = 0;

    // A staging (threads 0..127): 32 rows x 4 phys slots of 8 k
    const int arow = t >> 2, asp = t & 3;
    const bool adoA = t < 128;
    const size_t aXbase = (size_t)(gr0 + arow) * 1024 + (asp ^ (arow & 3)) * 8;
    const int aLds = arow * 32 + asp * 8;

    // B staging: 896 slots (384 h + 384 m + 128 l3), 4 guarded rounds
    int blvl[4]; size_t bsrc[4]; int blds[4]; bool bok[4];
    #pragma unroll
    for (int i = 0; i < 4; ++i) {
        int s = t + i * 256;
        bok[i] = s < 896;
        int lvl = (s < 384) ? 0 : (s < 768 ? 1 : 2);
        int cs = s - (lvl == 0 ? 0 : (lvl == 1 ? 384 : 768));
        int col = cs >> 2, sp = cs & 3;
        blvl[i] = lvl;
        int colRow = (lvl == 2) ? (side * 32 + col) : (side * 96 + col);
        bsrc[i] = (size_t)colRow * 1024 + (sp ^ (col & 3)) * 8;
        blds[i] = col * 32 + sp * 8;
    }

    const int wr0 = (w >= 2) ? 16 : 0;
    const bool isBoolWave = ((w & 1) == 0);
    const int kg = lane >> 4;
    const int frow = wr0 + (lane & 15);
    const int aoff = frow * 32 + (kg ^ (frow & 3)) * 8;

    f32x4 acc[4];
    #pragma unroll
    for (int i = 0; i < 4; ++i) acc[i] = f32x4{0.f, 0.f, 0.f, 0.f};

    // prologue: stage kc=0 into buf0
    if (adoA) {
        f4 v0 = *(const f4*)&X[aXbase + 0];
        f4 v1 = *(const f4*)&X[aXbase + 4];
        u16x8 h, m, l;
        #pragma unroll
        for (int j = 0; j < 8; ++j) {
            float x = (j < 4) ? f4c(v0, j) : f4c(v1, j - 4);
            unsigned short hb_ = f2bf(x);
            float r1 = x - bf2f(hb_);
            unsigned short mb_ = f2bf(r1);
            float r2 = r1 - bf2f(mb_);
            h[j] = hb_; m[j] = mb_; l[j] = f2bf(r2);
        }
        *(u16x8*)&Ah[0][aLds] = h; *(u16x8*)&Am[0][aLds] = m; *(u16x8*)&Al[0][aLds] = l;
    }
    #pragma unroll
    for (int i = 0; i < 4; ++i) if (bok[i]) {
        const unsigned short* sp_ = (blvl[i] == 0) ? Wh : (blvl[i] == 1 ? Wm : Wl3);
        u16x8 v = *(const u16x8*)&sp_[bsrc[i]];
        if (blvl[i] == 0)      *(u16x8*)&BhS[0][blds[i]] = v;
        else if (blvl[i] == 1) *(u16x8*)&BmS[0][blds[i]] = v;
        else                   *(u16x8*)&BlS[0][blds[i]] = v;
    }
    __syncthreads();

    for (int kc = 0; kc < 32; ++kc) {
        const int cur = kc & 1, nxt = cur ^ 1;
        const bool more = (kc + 1) < 32;
        f4 av0, av1;
        u16x8 bv[4];
        if (more) {
            const size_t ko = (size_t)(kc + 1) * 32;
            if (adoA) {
                av0 = *(const f4*)&X[aXbase + ko];
                av1 = *(const f4*)&X[aXbase + ko + 4];
            }
            #pragma unroll
            for (int i = 0; i < 4; ++i) if (bok[i]) {
                const unsigned short* sp_ = (blvl[i] == 0) ? Wh : (blvl[i] == 1 ? Wm : Wl3);
                bv[i] = *(const u16x8*)&sp_[bsrc[i] + ko];
            }
        }
        // compute on cur
        s16x8 a1 = *(const s16x8*)&Ah[cur][aoff];
        s16x8 a2 = *(const s16x8*)&Am[cur][aoff];
        if (isBoolWave) {
            s16x8 a3 = *(const s16x8*)&Al[cur][aoff];
            #pragma unroll
            for (int cf = 0; cf < 2; ++cf) {
                int col = 16 * cf + (lane & 15);
                int boff = col * 32 + (kg ^ (col & 3)) * 8;
                s16x8 b1 = *(const s16x8*)&BhS[cur][boff];
                s16x8 b2 = *(const s16x8*)&BmS[cur][boff];
                s16x8 b3 = *(const s16x8*)&BlS[cur][boff];
                acc[cf] = MFMA16(a1, b1, acc[cf]);
                acc[cf] = MFMA16(a1, b2, acc[cf]);
                acc[cf] = MFMA16(a2, b1, acc[cf]);
                acc[cf] = MFMA16(a2, b2, acc[cf]);
                acc[cf] = MFMA16(a1, b3, acc[cf]);
                acc[cf] = MFMA16(a3, b1, acc[cf]);
            }
        } else {
            #pragma unroll
            for (int cf = 0; cf < 4; ++cf) {
                int col = 32 + 16 * cf + (lane & 15);
                int boff = col * 32 + (kg ^ (col & 3)) * 8;
                s16x8 b1 = *(const s16x8*)&BhS[cur][boff];
                s16x8 b2 = *(const s16x8*)&BmS[cur][boff];
                acc[cf] = MFMA16(a1, b1, acc[cf]);
                acc[cf] = MFMA16(a1, b2, acc[cf]);
                acc[cf] = MFMA16(a2, b1, acc[cf]);
            }
        }
        if (more) {
            if (adoA) {
                u16x8 h, m, l;
                #pragma unroll
                for (int j = 0; j < 8; ++j) {
                    float x = (j < 4) ? f4c(av0, j) : f4c(av1, j - 4);
                    unsigned short hb_ = f2bf(x);
                    float r1 = x - bf2f(hb_);
                    unsigned short mb_ = f2bf(r1);
                    float r2 = r1 - bf2f(mb_);
                    h[j] = hb_; m[j] = mb_; l[j] = f2bf(r2);
                }
                *(u16x8*)&Ah[nxt][aLds] = h; *(u16x8*)&Am[nxt][aLds] = m; *(u16x8*)&Al[nxt][aLds] = l;
            }
            #pragma unroll
            for (int i = 0; i < 4; ++i) if (bok[i]) {
                if (blvl[i] == 0)      *(u16x8*)&BhS[nxt][blds[i]] = bv[i];
                else if (blvl[i] == 1) *(u16x8*)&BmS[nxt][blds[i]] = bv[i];
                else                   *(u16x8*)&BlS[nxt][blds[i]] = bv[i];
            }
        }
        __syncthreads();
    }

    // epilogue
    if (isBoolWave) {
        #pragma unroll
        for (int cf = 0; cf < 2; ++cf)
            #pragma unroll
            for (int r = 0; r < 4; ++r) {
                unsigned long long bm = __ballot(acc[cf][r] > 0.f);
                if (lane == 0) {
                    #pragma unroll
                    for (int g = 0; g < 4; ++g)
                        sb[wr0 + g * 4 + r] |=
                            (unsigned)((bm >> (16 * g)) & 0xFFFFull) << (16 * cf);
                }
            }
    } else {
        #pragma unroll
        for (int cf = 0; cf < 4; ++cf)
            #pragma unroll
            for (int r = 0; r < 4; ++r) {
                int rowg = gr0 + wr0 + kg * 4 + r;
                int c = 16 * (cf & 1) + (lane & 15);
                if (cf < 2) Tt[(size_t)rowg * 32 + c] = acc[cf][r];
                else        Tr[(size_t)rowg * 32 + c] = acc[cf][r];
            }
    }
    __syncthreads();
    if (t < 32) Tb[gr0 + t] = sb[t];
}

// ---------------- proj_v: MFMA, writes transposed bf16 hi/lo VpT images ----------------

__global__ __launch_bounds__(256)
void proj_v_kernel(const float* __restrict__ V,
                   const unsigned short* __restrict__ Wvh, const unsigned short* __restrict__ Wvm,
                   unsigned short* __restrict__ VpTh, unsigned short* __restrict__ VpTl) {
    const int t = threadIdx.x, lane = t & 63, w = t >> 6;
    const int gr0 = blockIdx.x * 32;
    const int b = gr0 >> 10, m_in_b = gr0 & 1023;

    __shared__ unsigned short Ah[2][1024], Am[2][1024];
    __shared__ unsigned short BhS[2][4096], BmS[2][4096];
    __shared__ float T[32][132];

    const int arow = t >> 2, asp = t & 3;
    const bool adoA = t < 128;
    const size_t aXbase = (size_t)(gr0 + arow) * 1024 + (asp ^ (arow & 3)) * 8;
    const int aLds = arow * 32 + asp * 8;

    int blvl[4]; size_t bsrc[4]; int blds[4];
    #pragma unroll
    for (int i = 0; i < 4; ++i) {
        int s = t + i * 256;
        blvl[i] = s >> 9;
        int cs = s & 511;
        int col = cs >> 2, sp = cs & 3;
        bsrc[i] = (size_t)col * 1024 + (sp ^ (col & 3)) * 8;
        blds[i] = col * 32 + sp * 8;
    }

    const int wr0 = (w >= 2) ? 16 : 0;
    const int hbase = (w & 1) ? 64 : 0;
    const int kg = lane >> 4;
    const int frow = wr0 + (lane & 15);
    const int aoff = frow * 32 + (kg ^ (frow & 3)) * 8;

    f32x4 acc[4];
    #pragma unroll
    for (int i = 0; i < 4; ++i) acc[i] = f32x4{0.f, 0.f, 0.f, 0.f};

    if (adoA) {
        f4 v0 = *(const f4*)&V[aXbase + 0];
        f4 v1 = *(const f4*)&V[aXbase + 4];
        u16x8 h, m;
        #pragma unroll
        for (int j = 0; j < 8; ++j) {
            float x = (j < 4) ? f4c(v0, j) : f4c(v1, j - 4);
            unsigned short hb_ = f2bf(x);
            h[j] = hb_; m[j] = f2bf(x - bf2f(hb_));
        }
        *(u16x8*)&Ah[0][aLds] = h; *(u16x8*)&Am[0][aLds] = m;
    }
    #pragma unroll
    for (int i = 0; i < 4; ++i) {
        const unsigned short* sp_ = blvl[i] ? Wvm : Wvh;
        u16x8 v = *(const u16x8*)&sp_[bsrc[i]];
        if (blvl[i]) *(u16x8*)&BmS[0][blds[i]] = v;
        else         *(u16x8*)&BhS[0][blds[i]] = v;
    }
    __syncthreads();

    for (int kc = 0; kc < 32; ++kc) {
        const int cur = kc & 1, nxt = cur ^ 1;
        const bool more = (kc + 1) < 32;
        f4 av0, av1;
        u16x8 bv[4];
        if (more) {
            const size_t ko = (size_t)(kc + 1) * 32;
            if (adoA) {
                av0 = *(const f4*)&V[aXbase + ko];
                av1 = *(const f4*)&V[aXbase + ko + 4];
            }
            #pragma unroll
            for (int i = 0; i < 4; ++i) {
                const unsigned short* sp_ = blvl[i] ? Wvm : Wvh;
                bv[i] = *(const u16x8*)&sp_[bsrc[i] + ko];
            }
        }
        s16x8 a1 = *(const s16x8*)&Ah[cur][aoff];
        s16x8 a2 = *(const s16x8*)&Am[cur][aoff];
        #pragma unroll
        for (int cf = 0; cf < 4; ++cf) {
            int col = hbase + 16 * cf + (lane & 15);
            int boff = col * 32 + (kg ^ (col & 3)) * 8;
            s16x8 b1 = *(const s16x8*)&BhS[cur][boff];
            s16x8 b2 = *(const s16x8*)&BmS[cur][boff];
            acc[cf] = MFMA16(a1, b1, acc[cf]);
            acc[cf] = MFMA16(a1, b2, acc[cf]);
            acc[cf] = MFMA16(a2, b1, acc[cf]);
        }
        if (more) {
            if (adoA) {
                u16x8 h, m;
                #pragma unroll
                for (int j = 0; j < 8; ++j) {
                    float x = (j < 4) ? f4c(av0, j) : f4c(av1, j - 4);
                    unsigned short hb_ = f2bf(x);
                    h[j] = hb_; m[j] = f2bf(x - bf2f(hb_));
                }
                *(u16x8*)&Ah[nxt][aLds] = h; *(u16x8*)&Am[nxt][aLds] = m;
            }
            #pragma unroll
            for (int i = 0; i < 4; ++i) {
                if (blvl[i]) *(u16x8*)&BmS[nxt][blds[i]] = bv[i];
                else         *(u16x8*)&BhS[nxt][blds[i]] = bv[i];
            }
        }
        __syncthreads();
    }

    // epilogue: transpose via LDS, write VpT hi/lo
    #pragma unroll
    for (int cf = 0; cf < 4; ++cf)
        #pragma unroll
        for (int r = 0; r < 4; ++r)
            T[wr0 + kg * 4 + r][hbase + 16 * cf + (lane & 15)] = acc[cf][r];
    __syncthreads();
    const int h = t >> 1, m0 = (t & 1) * 16;
    u16x8 hh[2], ll[2];
    #pragma unroll
    for (int i = 0; i < 16; ++i) {
        float x = T[m0 + i][h];
        unsigned short hb_ = f2bf(x);
        hh[i >> 3][i & 7] = hb_;
        ll[i >> 3][i & 7] = f2bf(x - bf2f(hb_));
    }
    size_t obase = (size_t)(b * 128 + h) * 1024 + m_in_b + m0;
    *(u16x8*)&VpTh[obase] = hh[0]; *(u16x8*)&VpTh[obase + 8] = hh[1];
    *(u16x8*)&VpTl[obase] = ll[0]; *(u16x8*)&VpTl[obase + 8] = ll[1];
}

// ---------------- fused sims -> raw scores (64n x 64m tiles) ----------------

__global__ __launch_bounds__(256)
void scores_kernel(const float* __restrict__ Qt, const float* __restrict__ Qr,
                   const float* __restrict__ Kt, const float* __restrict__ Kr,
                   const unsigned* __restrict__ Qbits, const unsigned* __restrict__ Kbits,
                   const float* __restrict__ fw, float* __restrict__ attn) {
    const int t = threadIdx.x;
    const int m0 = blockIdx.x * 64;
    const int n0 = blockIdx.y * 64;
    const int b  = blockIdx.z;

    __shared__ float Qt_s[64][36], Qr_s[64][36];
    __shared__ float KtT[32][68],  KrT[32][68];
    __shared__ unsigned qb_s[64], kb_s[64];

    #pragma unroll
    for (int k2 = 0; k2 < 2; ++k2) {
        int idx = t + k2 * 256;
        int r = idx >> 3, c4 = idx & 7;
        *(f4*)&Qt_s[r][c4 * 4] = *(const f4*)&Qt[(size_t)(b * 1024 + n0 + r) * 32 + c4 * 4];
        *(f4*)&Qr_s[r][c4 * 4] = *(const f4*)&Qr[(size_t)(b * 1024 + n0 + r) * 32 + c4 * 4];
        f4 vt = *(const f4*)&Kt[(size_t)(b * 1024 + m0 + r) * 32 + c4 * 4];
        f4 vr = *(const f4*)&Kr[(size_t)(b * 1024 + m0 + r) * 32 + c4 * 4];
        KtT[c4 * 4 + 0][r] = vt.x; KtT[c4 * 4 + 1][r] = vt.y;
        KtT[c4 * 4 + 2][r] = vt.z; KtT[c4 * 4 + 3][r] = vt.w;
        KrT[c4 * 4 + 0][r] = vr.x; KrT[c4 * 4 + 1][r] = vr.y;
        KrT[c4 * 4 + 2][r] = vr.z; KrT[c4 * 4 + 3][r] = vr.w;
    }
    if (t < 64)       qb_s[t] = Qbits[b * 1024 + n0 + t];
    else if (t < 128) kb_s[t - 64] = Kbits[b * 1024 + m0 + (t - 64)];
    __syncthreads();

    const float f0 = fw[0], f1 = fw[1], f2 = fw[2];
    const float fm = fmaxf(f0, fmaxf(f1, f2));
    const float e0 = __expf(f0 - fm), e1 = __expf(f1 - fm), e2 = __expf(f2 - fm);
    const float wi = 1.f / (e0 + e1 + e2);
    const float w0 = e0 * wi, w1 = e1 * wi, w2 = e2 * wi;

    const int rg = t >> 4, mg = t & 15;

    float tacc[4][4], racc[4][4];
    #pragma unroll
    for (int i = 0; i < 4; ++i)
        #pragma unroll
        for (int j = 0; j < 4; ++j) { tacc[i][j] = -INFINITY; racc[i][j] = 0.f; }

    for (int d0 = 0; d0 < 32; d0 += 4) {
        f4 qt4[4], qr4[4];
        #pragma unroll
        for (int i = 0; i < 4; ++i) {
            qt4[i] = *(const f4*)&Qt_s[4 * rg + i][d0];
            qr4[i] = *(const f4*)&Qr_s[4 * rg + i][d0];
        }
        #pragma unroll
        for (int d2 = 0; d2 < 4; ++d2) {
            const f4 kt = *(const f4*)&KtT[d0 + d2][4 * mg];
            const f4 kr = *(const f4*)&KrT[d0 + d2][4 * mg];
            #pragma unroll
            for (int i = 0; i < 4; ++i) {
                const float qtv = f4c(qt4[i], d2);
                const float qrv = f4c(qr4[i], d2);
                tacc[i][0] = fmaxf(tacc[i][0], qtv + kt.x);
                tacc[i][1] = fmaxf(tacc[i][1], qtv + kt.y);
                tacc[i][2] = fmaxf(tacc[i][2], qtv + kt.z);
                tacc[i][3] = fmaxf(tacc[i][3], qtv + kt.w);
                racc[i][0] += qrv * kr.x;
                racc[i][1] += qrv * kr.y;
                racc[i][2] += qrv * kr.z;
                racc[i][3] += qrv * kr.w;
            }
        }
    }

    unsigned qb[4], kb[4];
    #pragma unroll
    for (int i = 0; i < 4; ++i) { qb[i] = qb_s[4 * rg + i]; kb[i] = kb_s[4 * mg + i]; }
    #pragma unroll
    for (int i = 0; i < 4; ++i) {
        float sj[4];
        #pragma unroll
        for (int j = 0; j < 4; ++j) {
            const float cnt = (float)(32 - __popc(qb[i] ^ kb[j]));
            sj[j] = (w0 * cnt + w1 * tacc[i][j] + w2 * racc[i][j]) * SCALE_F;
        }
        *(f4*)&attn[(size_t)(b * 1024 + n0 + 4 * rg + i) * 1024 + m0 + 4 * mg] =
            make_float4(sj[0], sj[1], sj[2], sj[3]);
    }
}

// ---------------- per-row masked softmax (in place on attn) ----------------

__global__ __launch_bounds__(256)
void softmax_kernel(float* __restrict__ attn, const int* __restrict__ mask) {
    const int row = blockIdx.x;
    const int t = threadIdx.x;
    const f4  s4 = ((const f4*)attn)[(size_t)row * 256 + t];
    const int4 m4 = ((const int4*)mask)[(size_t)row * 256 + t];
    const float v0 = m4.x ? s4.x : -INFINITY;
    const float v1 = m4.y ? s4.y : -INFINITY;
    const float v2 = m4.z ? s4.z : -INFINITY;
    const float v3 = m4.w ? s4.w : -INFINITY;

    float tm = fmaxf(fmaxf(v0, v1), fmaxf(v2, v3));
    #pragma unroll
    for (int off = 32; off >= 1; off >>= 1) tm = fmaxf(tm, __shfl_xor(tm, off, 64));
    __shared__ float rmax[4], rsum[4];
    if ((t & 63) == 0) rmax[t >> 6] = tm;
    __syncthreads();
    const float gm = fmaxf(fmaxf(rmax[0], rmax[1]), fmaxf(rmax[2], rmax[3]));

    const float x0 = m4.x ? __expf(v0 - gm) : 0.f;
    const float x1 = m4.y ? __expf(v1 - gm) : 0.f;
    const float x2 = m4.z ? __expf(v2 - gm) : 0.f;
    const float x3 = m4.w ? __expf(v3 - gm) : 0.f;
    float ts = (x0 + x1) + (x2 + x3);
    #pragma unroll
    for (int off = 32; off >= 1; off >>= 1) ts += __shfl_xor(ts, off, 64);
    if ((t & 63) == 0) rsum[t >> 6] = ts;
    __syncthreads();
    const float inv = 1.f / (((rsum[0] + rsum[1]) + (rsum[2] + rsum[3])));

    ((f4*)attn)[(size_t)row * 256 + t] = make_float4(x0 * inv, x1 * inv, x2 * inv, x3 * inv);
}

// ---------------- pv: MFMA bf16x3 from f32 attn, writes out directly ----------------

__global__ __launch_bounds__(256)
void pv_kernel(const float* __restrict__ attn,
               const unsigned short* __restrict__ VpTh, const unsigned short* __restrict__ VpTl,
               float* __restrict__ out) {
    const int t = threadIdx.x, lane = t & 63, w = t >> 6;
    const int gr0 = blockIdx.x * 32;
    const int b = gr0 >> 10;

    __shared__ unsigned short Ah[2][1024], Am[2][1024];
    __shared__ unsigned short BhS[2][4096], BmS[2][4096];

    const int arow = t >> 2, asp = t & 3;
    const bool adoA = t < 128;
    const size_t aXbase = (size_t)(gr0 + arow) * 1024 + (asp ^ (arow & 3)) * 8;
    const int aLds = arow * 32 + asp * 8;

    int blvl[4]; size_t bsrc[4]; int blds[4];
    #pragma unroll
    for (int i = 0; i < 4; ++i) {
        int s = t + i * 256;
        blvl[i] = s >> 9;
        int cs = s & 511;
        int col = cs >> 2, sp = cs & 3;
        bsrc[i] = (size_t)(b * 128 + col) * 1024 + (sp ^ (col & 3)) * 8;
        blds[i] = col * 32 + sp * 8;
    }

    const int wr0 = (w >= 2) ? 16 : 0;
    const int hbase = (w & 1) ? 64 : 0;
    const int kg = lane >> 4;
    const int frow = wr0 + (lane & 15);
    const int aoff = frow * 32 + (kg ^ (frow & 3)) * 8;

    f32x4 acc[4];
    #pragma unroll
    for (int i = 0; i < 4; ++i) acc[i] = f32x4{0.f, 0.f, 0.f, 0.f};

    if (adoA) {
        f4 v0 = *(const f4*)&attn[aXbase + 0];
        f4 v1 = *(const f4*)&attn[aXbase + 4];
        u16x8 h, m;
        #pragma unroll
        for (int j = 0; j < 8; ++j) {
            float x = (j < 4) ? f4c(v0, j) : f4c(v1, j - 4);
            unsigned short hb_ = f2bf(x);
            h[j] = hb_; m[j] = f2bf(x - bf2f(hb_));
        }
        *(u16x8*)&Ah[0][aLds] = h; *(u16x8*)&Am[0][aLds] = m;
    }
    #pragma unroll
    for (int i = 0; i < 4; ++i) {
        const unsigned short* sp_ = blvl[i] ? VpTl : VpTh;
        u16x8 v = *(const u16x8*)&sp_[bsrc[i]];
        if (blvl[i]) *(u16x8*)&BmS[0][blds[i]] = v;
        else         *(u16x8*)&BhS[0][blds[i]] = v;
    }
    __syncthreads();

    for (int kc = 0; kc < 32; ++kc) {
        const int cur = kc & 1, nxt = cur ^ 1;
        const bool more = (kc + 1) < 32;
        f4 av0, av1;
        u16x8 bv[4];
        if (more) {
            const size_t ko = (size_t)(kc + 1) * 32;
            if (adoA) {
                av0 = *(const f4*)&attn[aXbase + ko];
                av1 = *(const f4*)&attn[aXbase + ko + 4];
            }
            #pragma unroll
            for (int i = 0; i < 4; ++i) {
                const unsigned short* sp_ = blvl[i] ? VpTl : VpTh;
                bv[i] = *(const u16x8*)&sp_[bsrc[i] + ko];
            }
        }
        s16x8 a1 = *(const s16x8*)&Ah[cur][aoff];
        s16x8 a2 = *(const s16x8*)&Am[cur][aoff];
        #pragma unroll
        for (int cf = 0; cf < 4; ++cf) {
            int col = hbase + 16 * cf + (lane & 15);
            int boff = col * 32 + (kg ^ (col & 3)) * 8;
            s16x8 b1 = *(const s16x8*)&BhS[cur][boff];
            s16x8 b2 = *(const s16x8*)&BmS[cur][boff];
            acc[cf] = MFMA16(a1, b1, acc[cf]);
            acc[cf] = MFMA16(a1, b2, acc[cf]);
            acc[cf] = MFMA16(a2, b1, acc[cf]);
        }
        if (more) {
            if (adoA) {
                u16x8 h, m;
                #pragma unroll
                for (int j = 0; j < 8; ++j) {
                    float x = (j < 4) ? f4c(av0, j) : f4c(av1, j - 4);
                    unsigned short hb_ = f2bf(x);
                    h[j] = hb_; m[j] = f2bf(x - bf2f(hb_));
                }
                *(u16x8*)&Ah[nxt][aLds] = h; *(u16x8*)&Am[nxt][aLds] = m;
            }
            #pragma unroll
            for (int i = 0; i < 4; ++i) {
                if (blvl[i]) *(u16x8*)&BmS[nxt][blds[i]] = bv[i];
                else         *(u16x8*)&BhS[nxt][blds[i]] = bv[i];
            }
        }
        __syncthreads();
    }

    #pragma unroll
    for (int cf = 0; cf < 4; ++cf)
        #pragma unroll
        for (int r = 0; r < 4; ++r)
            out[(size_t)(gr0 + wr0 + kg * 4 + r) * 128 + hbase + 16 * cf + (lane & 15)] =
                acc[cf][r];
}

// ---------------- launch ----------------

extern "C" void kernel_launch(void* const* d_in, const int* in_sizes, int n_in,
                              void* d_out, int out_size, void* d_ws, size_t ws_size,
                              hipStream_t stream) {
    const float* Q   = (const float*)d_in[0];
    const float* K   = (const float*)d_in[1];
    const float* V   = (const float*)d_in[2];
    const float* Wqb = (const float*)d_in[3];
    const float* Wkb = (const float*)d_in[4];
    const float* Wqt = (const float*)d_in[5];
    const float* Wkt = (const float*)d_in[6];
    const float* Wqr = (const float*)d_in[7];
    const float* Wkr = (const float*)d_in[8];
    const float* Wv  = (const float*)d_in[9];
    const float* fw  = (const float*)d_in[10];
    const int*  mask = (const int*)d_in[11];

    float* ws = (float*)d_ws;
    float* QtW = ws;                          // [8192][32]
    float* QrW = QtW + 262144;
    float* KtW = QrW + 262144;
    float* KrW = KtW + 262144;
    unsigned* QbitsW = (unsigned*)(KrW + 262144);    // [8192]
    unsigned* KbitsW = QbitsW + 8192;
    unsigned short* Wh   = (unsigned short*)(KbitsW + 8192); // [192][1024]
    unsigned short* Wm   = Wh + 196608;
    unsigned short* Wl3  = Wm + 196608;       // [64][1024]
    unsigned short* Wvh  = Wl3 + 65536;       // [128][1024]
    unsigned short* Wvm  = Wvh + 131072;
    unsigned short* VpTh = Wvm + 131072;      // [8*128][1024]
    unsigned short* VpTl = VpTh + 1048576;

    float* out  = (float*)d_out;              // [8192][128]
    float* attn = out + 1048576;              // [8192][1024]

    conv_w_kernel<<<40, 256, 0, stream>>>(Wqb, Wkb, Wqt, Wkt, Wqr, Wkr, Wv,
                                          Wh, Wm, Wl3, Wvh, Wvm);
    proj_qk_kernel<<<dim3(256, 2), 256, 0, stream>>>(Q, K, Wh, Wm, Wl3,
                                                     QtW, QrW, KtW, KrW, QbitsW, KbitsW);
    proj_v_kernel<<<256, 256, 0, stream>>>(V, Wvh, Wvm, VpTh, VpTl);
    scores_kernel<<<dim3(16, 16, 8), 256, 0, stream>>>(QtW, QrW, KtW, KrW,
                                                       QbitsW, KbitsW, fw, attn);
    softmax_kernel<<<8192, 256, 0, stream>>>(attn, mask);
    pv_kernel<<<256, 256, 0, stream>>>(attn, VpTh, VpTl, out);
}

// Round 3
// 278.810 us; speedup vs baseline: 1.1250x; 1.0216x over previous
//
#include <hip/hip_runtime.h>
#include <hip/hip_fp16.h>
#include <stdint.h>
#include <math.h>

// ProductMonoidHead — round 3: B-resident MFMA GEMMs, packed-f16 tropical.
// B=8 N=M=1024 D=1024 MB=32 H=128.
// d_out = out[8192][128] f32 ++ attn[8192][1024] f32.

#define SCALE_F 0.17677669529663687f

typedef float4 f4;
typedef unsigned int uint_t;
typedef __attribute__((ext_vector_type(8))) short s16x8;
typedef __attribute__((ext_vector_type(8))) unsigned short u16x8;
typedef __attribute__((ext_vector_type(4))) float f32x4;

__device__ __forceinline__ unsigned short f2bf(float x) {
    unsigned u = __float_as_uint(x);
    return (unsigned short)((u + 0x7FFFu + ((u >> 16) & 1u)) >> 16);
}
__device__ __forceinline__ float bf2f(unsigned short h) {
    return __uint_as_float(((unsigned)h) << 16);
}
__device__ __forceinline__ float f4c(const f4 v, int i) {
    return i == 0 ? v.x : (i == 1 ? v.y : (i == 2 ? v.z : v.w));
}
__device__ __forceinline__ unsigned pk_add(unsigned a, unsigned b) {
    unsigned r;
    asm("v_pk_add_f16 %0, %1, %2" : "=v"(r) : "v"(a), "v"(b));
    return r;
}
__device__ __forceinline__ unsigned pk_max(unsigned a, unsigned b) {
    unsigned r;
    asm("v_pk_max_f16 %0, %1, %2" : "=v"(r) : "v"(a), "v"(b));
    return r;
}
__device__ __forceinline__ float h2f(unsigned short u) {
    __half h;
    *reinterpret_cast<unsigned short*>(&h) = u;
    return __half2float(h);
}
__device__ __forceinline__ unsigned short f2h(float x) {
    __half h = __float2half(x);
    return *reinterpret_cast<unsigned short*>(&h);
}

#define MFMA16(a, b, c) __builtin_amdgcn_mfma_f32_16x16x32_bf16((a), (b), (c), 0, 0, 0)

// ---------------- conv_w: build transposed bf16 W images (unchanged from R2) ----------------
// Wh/Wm: [side*96+col][1024]  (col 0-31 bool, 32-63 trop, 64-95 real)
// Wl3:   [side*32+col][1024]  (bool 3rd level);  Wvh/Wvm: [h=128][1024]

__global__ __launch_bounds__(256)
void conv_w_kernel(const float* __restrict__ Wqb, const float* __restrict__ Wkb,
                   const float* __restrict__ Wqt, const float* __restrict__ Wkt,
                   const float* __restrict__ Wqr, const float* __restrict__ Wkr,
                   const float* __restrict__ Wv,
                   unsigned short* __restrict__ Wh, unsigned short* __restrict__ Wm,
                   unsigned short* __restrict__ Wl3,
                   unsigned short* __restrict__ Wvh, unsigned short* __restrict__ Wvm) {
    __shared__ float T[256][33];
    const int t = threadIdx.x;
    const int bid = blockIdx.x;
    const float* src;
    int kb, outRowBase, srcStride, srcColBase, side = 0;
    bool isQK, isBool;
    if (bid < 24) {
        side = bid / 12;
        int cb = (bid % 12) / 4;
        kb = bid & 3;
        const float* mats[6] = {Wqb, Wqt, Wqr, Wkb, Wkt, Wkr};
        src = mats[side * 3 + cb];
        srcStride = 32; srcColBase = 0;
        outRowBase = side * 96 + cb * 32;
        isQK = true; isBool = (cb == 0);
    } else {
        int v = bid - 24;
        int hb = v >> 2; kb = v & 3;
        src = Wv; srcStride = 128; srcColBase = hb * 32;
        outRowBase = hb * 32;
        isQK = false; isBool = false;
    }
    #pragma unroll
    for (int i = 0; i < 8; ++i) {
        int idx = t + i * 256;
        int r = idx >> 3, c4 = idx & 7;
        f4 v = *(const f4*)&src[(size_t)(kb * 256 + r) * srcStride + srcColBase + c4 * 4];
        T[r][c4 * 4 + 0] = v.x; T[r][c4 * 4 + 1] = v.y;
        T[r][c4 * 4 + 2] = v.z; T[r][c4 * 4 + 3] = v.w;
    }
    __syncthreads();
    const int col = t >> 3, kseg = t & 7;
    unsigned short* dh = isQK ? Wh : Wvh;
    unsigned short* dm = isQK ? Wm : Wvm;
    size_t obase = (size_t)(outRowBase + col) * 1024 + kb * 256 + kseg * 32;
    u16x8 ph[4], pm[4], pl[4];
    #pragma unroll
    for (int i = 0; i < 32; ++i) {
        float x = T[kseg * 32 + i][col];
        unsigned short hb_ = f2bf(x);
        float r1 = x - bf2f(hb_);
        unsigned short mb_ = f2bf(r1);
        float r2 = r1 - bf2f(mb_);
        ph[i >> 3][i & 7] = hb_;
        pm[i >> 3][i & 7] = mb_;
        pl[i >> 3][i & 7] = f2bf(r2);
    }
    #pragma unroll
    for (int i = 0; i < 4; ++i) {
        *(u16x8*)&dh[obase + i * 8] = ph[i];
        *(u16x8*)&dm[obase + i * 8] = pm[i];
    }
    if (isBool) {
        size_t lbase = (size_t)(side * 32 + col) * 1024 + kb * 256 + kseg * 32;
        #pragma unroll
        for (int i = 0; i < 4; ++i) *(u16x8*)&Wl3[lbase + i * 8] = pl[i];
    }
}

// ---------------- proj: unified Q/K/V, B resident per 128-K chunk, A in regs ----------------
// blocks 0..255: QK (side=bx>>7, 64-row tiles). blocks 256..511: V (32-row tiles).

__global__ __launch_bounds__(256)
void proj_kernel(const float* __restrict__ Q, const float* __restrict__ K,
                 const float* __restrict__ V,
                 const unsigned short* __restrict__ Wh, const unsigned short* __restrict__ Wm,
                 const unsigned short* __restrict__ Wl3,
                 const unsigned short* __restrict__ Wvh, const unsigned short* __restrict__ Wvm,
                 unsigned short* __restrict__ Qt_q, unsigned short* __restrict__ Kt_q,
                 unsigned short* __restrict__ Qrh, unsigned short* __restrict__ Qrm,
                 unsigned short* __restrict__ Krh, unsigned short* __restrict__ Krm,
                 uint_t* __restrict__ Qbits, uint_t* __restrict__ Kbits,
                 unsigned short* __restrict__ VphT, unsigned short* __restrict__ VpmT) {
    __shared__ unsigned short BH[16384], BM[16384], BL[4096];  // 32+32+8 KB
    __shared__ uint_t sb[64];
    const int t = threadIdx.x, lane = t & 63, w = t >> 6;
    const int g = lane >> 4, l15 = lane & 15;
    const int bx = blockIdx.x;
    const bool isV = bx >= 256;
    const int side = isV ? 2 : (bx >> 7);
    const int tile = isV ? (bx - 256) : (bx & 127);
    const float* __restrict__ X = (side == 0) ? Q : (side == 1 ? K : V);
    const int row0 = isV ? tile * 32 : tile * 64;
    const int rowh = isV ? (w & 1) * 16 : w * 16;   // wave's 16-row group offset
    const int hbase = isV ? (w >> 1) * 64 : 0;
    const int arowg = row0 + rowh + l15;            // A-frag row (global, within matrix)
    const float* __restrict__ Xrow = X + (size_t)arowg * 1024;

    if (t < 64) sb[t] = 0;

    f32x4 acc[8];
    #pragma unroll
    for (int i = 0; i < 8; ++i) acc[i] = f32x4{0.f, 0.f, 0.f, 0.f};

    for (int c = 0; c < 8; ++c) {
        const int k0 = c * 128;
        // A prefetch for the whole chunk (hidden behind fill + barriers)
        f4 ar[8];
        #pragma unroll
        for (int ks = 0; ks < 4; ++ks) {
            ar[2 * ks]     = *(const f4*)&Xrow[k0 + ks * 32 + g * 8];
            ar[2 * ks + 1] = *(const f4*)&Xrow[k0 + ks * 32 + g * 8 + 4];
        }
        __syncthreads();   // previous chunk's B reads complete
        if (!isV) {
            #pragma unroll
            for (int i = 0; i < 14; ++i) {
                int s = t + i * 256;
                int col, ks; const unsigned short* src; char* dp;
                if (s < 1536)      { col = s >> 4; ks = s & 15;
                    src = &Wh[(size_t)(side * 96 + col) * 1024 + k0 + ks * 8]; dp = (char*)BH; }
                else if (s < 3072) { int s2 = s - 1536; col = s2 >> 4; ks = s2 & 15;
                    src = &Wm[(size_t)(side * 96 + col) * 1024 + k0 + ks * 8]; dp = (char*)BM; }
                else               { int s2 = s - 3072; col = s2 >> 4; ks = s2 & 15;
                    src = &Wl3[(size_t)(side * 32 + col) * 1024 + k0 + ks * 8]; dp = (char*)BL; }
                u16x8 v = *(const u16x8*)src;
                *(u16x8*)(dp + col * 256 + ((ks * 16) ^ ((col & 7) << 4))) = v;
            }
        } else {
            #pragma unroll
            for (int i = 0; i < 16; ++i) {
                int s = t + i * 256;
                int col, ks; const unsigned short* src; char* dp;
                if (s < 2048) { col = s >> 4; ks = s & 15;
                    src = &Wvh[(size_t)col * 1024 + k0 + ks * 8]; dp = (char*)BH; }
                else          { int s2 = s - 2048; col = s2 >> 4; ks = s2 & 15;
                    src = &Wvm[(size_t)col * 1024 + k0 + ks * 8]; dp = (char*)BM; }
                u16x8 v = *(const u16x8*)src;
                *(u16x8*)(dp + col * 256 + ((ks * 16) ^ ((col & 7) << 4))) = v;
            }
        }
        __syncthreads();

        #pragma unroll
        for (int ks = 0; ks < 4; ++ks) {
            u16x8 ah, am, al;
            #pragma unroll
            for (int j = 0; j < 8; ++j) {
                float x = (j < 4) ? f4c(ar[2 * ks], j) : f4c(ar[2 * ks + 1], j - 4);
                unsigned short hb_ = f2bf(x);
                float r1 = x - bf2f(hb_);
                unsigned short mb_ = f2bf(r1);
                ah[j] = hb_; am[j] = mb_;
                al[j] = f2bf(r1 - bf2f(mb_));
            }
            s16x8 a1 = (s16x8)ah, a2 = (s16x8)am;
            const int kbyte = (ks * 4 + g) * 16;
            if (!isV) {
                s16x8 a3 = (s16x8)al;
                #pragma unroll
                for (int cf = 0; cf < 2; ++cf) {      // bool: 5-product
                    int col = cf * 16 + l15;
                    int off = col * 256 + (kbyte ^ ((col & 7) << 4));
                    s16x8 bh = *(s16x8*)((char*)BH + off);
                    s16x8 bm = *(s16x8*)((char*)BM + off);
                    s16x8 bl = *(s16x8*)((char*)BL + off);
                    acc[cf] = MFMA16(a1, bh, acc[cf]);
                    acc[cf] = MFMA16(a1, bm, acc[cf]);
                    acc[cf] = MFMA16(a2, bh, acc[cf]);
                    acc[cf] = MFMA16(a2, bm, acc[cf]);
                    acc[cf] = MFMA16(a3, bh, acc[cf]);
                }
                #pragma unroll
                for (int cf = 2; cf < 4; ++cf) {      // trop: 1-product
                    int col = cf * 16 + l15;
                    int off = col * 256 + (kbyte ^ ((col & 7) << 4));
                    s16x8 bh = *(s16x8*)((char*)BH + off);
                    acc[cf] = MFMA16(a1, bh, acc[cf]);
                }
                #pragma unroll
                for (int cf = 4; cf < 6; ++cf) {      // real: 3-product
                    int col = cf * 16 + l15;
                    int off = col * 256 + (kbyte ^ ((col & 7) << 4));
                    s16x8 bh = *(s16x8*)((char*)BH + off);
                    s16x8 bm = *(s16x8*)((char*)BM + off);
                    acc[cf] = MFMA16(a1, bh, acc[cf]);
                    acc[cf] = MFMA16(a1, bm, acc[cf]);
                    acc[cf] = MFMA16(a2, bh, acc[cf]);
                }
            } else {
                #pragma unroll
                for (int cf = 0; cf < 4; ++cf) {      // V: 3-product
                    int col = hbase + cf * 16 + l15;
                    int off = col * 256 + (kbyte ^ ((col & 7) << 4));
                    s16x8 bh = *(s16x8*)((char*)BH + off);
                    s16x8 bm = *(s16x8*)((char*)BM + off);
                    acc[cf] = MFMA16(a1, bh, acc[cf]);
                    acc[cf] = MFMA16(a1, bm, acc[cf]);
                    acc[cf] = MFMA16(a2, bh, acc[cf]);
                }
            }
        }
    }

    // ---------------- epilogue ----------------
    if (!isV) {
        // bool sign bits via ballot
        #pragma unroll
        for (int cf = 0; cf < 2; ++cf)
            #pragma unroll
            for (int r = 0; r < 4; ++r) {
                unsigned long long bm = __ballot(acc[cf][r] > 0.f);
                if (lane == 0) {
                    #pragma unroll
                    for (int gg = 0; gg < 4; ++gg)
                        sb[w * 16 + gg * 4 + r] |=
                            (uint_t)((bm >> (16 * gg)) & 0xFFFFull) << (16 * cf);
                }
            }
        unsigned short* Tt = side ? Kt_q : Qt_q;
        unsigned short* Rh = side ? Krh : Qrh;
        unsigned short* Rm = side ? Krm : Qrm;
        #pragma unroll
        for (int cf = 2; cf < 4; ++cf)
            #pragma unroll
            for (int r = 0; r < 4; ++r) {
                int grow = row0 + w * 16 + g * 4 + r;
                int tcol = (cf - 2) * 16 + l15;
                Tt[(size_t)grow * 32 + tcol] = f2h(acc[cf][r]);
            }
        #pragma unroll
        for (int cf = 4; cf < 6; ++cf)
            #pragma unroll
            for (int r = 0; r < 4; ++r) {
                int grow = row0 + w * 16 + g * 4 + r;
                int rcol = (cf - 4) * 16 + l15;
                float v = acc[cf][r];
                unsigned short h = f2bf(v);
                Rh[(size_t)grow * 32 + rcol] = h;
                Rm[(size_t)grow * 32 + rcol] = f2bf(v - bf2f(h));
            }
        __syncthreads();
        uint_t* Tb = side ? Kbits : Qbits;
        if (t < 64) Tb[row0 + t] = sb[t];
    } else {
        const int b = tile >> 5;
        const int mbase = (tile & 31) * 32 + (w & 1) * 16 + g * 4;
        #pragma unroll
        for (int cf = 0; cf < 4; ++cf) {
            int colh = hbase + cf * 16 + l15;
            ushort4 hv, mv;
            float v0 = acc[cf][0], v1 = acc[cf][1], v2 = acc[cf][2], v3 = acc[cf][3];
            unsigned short h0 = f2bf(v0), h1 = f2bf(v1), h2_ = f2bf(v2), h3 = f2bf(v3);
            hv = make_ushort4(h0, h1, h2_, h3);
            mv = make_ushort4(f2bf(v0 - bf2f(h0)), f2bf(v1 - bf2f(h1)),
                              f2bf(v2 - bf2f(h2_)), f2bf(v3 - bf2f(h3)));
            size_t ob = (size_t)(b * 128 + colh) * 1024 + mbase;
            *(ushort4*)&VphT[ob] = hv;
            *(ushort4*)&VpmT[ob] = mv;
        }
    }
}

// ---------------- scores: fused bool+trop(real pk-f16)+real(MFMA), mask folded ----------------

__global__ __launch_bounds__(256)
void scores_kernel(const unsigned short* __restrict__ Qt_q, const unsigned short* __restrict__ Kt_q,
                   const unsigned short* __restrict__ Qrh, const unsigned short* __restrict__ Qrm,
                   const unsigned short* __restrict__ Krh, const unsigned short* __restrict__ Krm,
                   const uint_t* __restrict__ Qbits, const uint_t* __restrict__ Kbits,
                   const int* __restrict__ mask, const float* __restrict__ fw,
                   float* __restrict__ attn) {
    const int t = threadIdx.x, lane = t & 63, w = t >> 6;
    const int g = lane >> 4, l15 = lane & 15;
    const int b = blockIdx.y, n0 = blockIdx.x * 16;
    const int rowA = b * 1024 + n0;

    s16x8 qrh = *(const s16x8*)&Qrh[(size_t)(rowA + l15) * 32 + g * 8];
    s16x8 qrm = *(const s16x8*)&Qrm[(size_t)(rowA + l15) * 32 + g * 8];
    uint_t qt[4][16], qb[4];
    #pragma unroll
    for (int r = 0; r < 4; ++r) {
        const uint_t* p = (const uint_t*)&Qt_q[(size_t)(rowA + 4 * g + r) * 32];
        #pragma unroll
        for (int j = 0; j < 16; ++j) qt[r][j] = p[j];
        qb[r] = Qbits[rowA + 4 * g + r];
    }
    const float f0 = fw[0], f1 = fw[1], f2 = fw[2];
    const float fm = fmaxf(f0, fmaxf(f1, f2));
    const float e0 = __expf(f0 - fm), e1 = __expf(f1 - fm), e2 = __expf(f2 - fm);
    const float wi = 1.f / (e0 + e1 + e2);
    const float w0 = e0 * wi, w1 = e1 * wi, w2 = e2 * wi;

    for (int i = 0; i < 16; ++i) {
        const int m0 = (w + 4 * i) * 16;
        const int mrow = b * 1024 + m0;
        const uint_t* ktp = (const uint_t*)&Kt_q[(size_t)(mrow + l15) * 32];
        uint_t kt[16];
        #pragma unroll
        for (int j = 0; j < 16; ++j) kt[j] = ktp[j];
        s16x8 krh = *(const s16x8*)&Krh[(size_t)(mrow + l15) * 32 + g * 8];
        s16x8 krm = *(const s16x8*)&Krm[(size_t)(mrow + l15) * 32 + g * 8];
        uint_t kb = Kbits[mrow + l15];
        int mk[4];
        #pragma unroll
        for (int r = 0; r < 4; ++r)
            mk[r] = mask[(size_t)(rowA + 4 * g + r) * 1024 + m0 + l15];

        f32x4 rc = f32x4{0.f, 0.f, 0.f, 0.f};
        rc = MFMA16(qrh, krh, rc);
        rc = MFMA16(qrh, krm, rc);
        rc = MFMA16(qrm, krh, rc);

        float trop[4];
        #pragma unroll
        for (int r = 0; r < 4; ++r) {
            unsigned a = pk_add(qt[r][0], kt[0]);
            #pragma unroll
            for (int j = 1; j < 16; ++j)
                a = pk_max(a, pk_add(qt[r][j], kt[j]));
            trop[r] = fmaxf(h2f((unsigned short)(a & 0xFFFF)),
                            h2f((unsigned short)(a >> 16)));
        }
        #pragma unroll
        for (int r = 0; r < 4; ++r) {
            float cnt = (float)(32 - __popc(qb[r] ^ kb));
            float s = (w0 * cnt + w1 * trop[r] + w2 * rc[r]) * SCALE_F;
            s = mk[r] ? s : -INFINITY;
            attn[(size_t)(rowA + 4 * g + r) * 1024 + m0 + l15] = s;
        }
    }
}

// ---------------- per-row softmax (mask already folded into raw scores) ----------------

__global__ __launch_bounds__(256)
void softmax_kernel(float* __restrict__ attn) {
    const int row = blockIdx.x;
    const int t = threadIdx.x;
    const f4 s4 = ((const f4*)attn)[(size_t)row * 256 + t];

    float tm = fmaxf(fmaxf(s4.x, s4.y), fmaxf(s4.z, s4.w));
    #pragma unroll
    for (int off = 32; off >= 1; off >>= 1) tm = fmaxf(tm, __shfl_xor(tm, off, 64));
    __shared__ float rmax[4], rsum[4];
    if ((t & 63) == 0) rmax[t >> 6] = tm;
    __syncthreads();
    const float gm = fmaxf(fmaxf(rmax[0], rmax[1]), fmaxf(rmax[2], rmax[3]));

    const float x0 = __expf(s4.x - gm);
    const float x1 = __expf(s4.y - gm);
    const float x2 = __expf(s4.z - gm);
    const float x3 = __expf(s4.w - gm);
    float ts = (x0 + x1) + (x2 + x3);
    #pragma unroll
    for (int off = 32; off >= 1; off >>= 1) ts += __shfl_xor(ts, off, 64);
    if ((t & 63) == 0) rsum[t >> 6] = ts;
    __syncthreads();
    const float inv = 1.f / ((rsum[0] + rsum[1]) + (rsum[2] + rsum[3]));

    ((f4*)attn)[(size_t)row * 256 + t] = make_float4(x0 * inv, x1 * inv, x2 * inv, x3 * inv);
}

// ---------------- pv: out = attn @ Vp, B(Vp) resident per 128-m chunk ----------------

__global__ __launch_bounds__(256)
void pv_kernel(const float* __restrict__ attn,
               const unsigned short* __restrict__ VphT, const unsigned short* __restrict__ VpmT,
               float* __restrict__ out) {
    __shared__ unsigned short BH[16384], BM[16384];   // 64 KB
    const int t = threadIdx.x, lane = t & 63, w = t >> 6;
    const int g = lane >> 4, l15 = lane & 15;
    const int b = blockIdx.y, n0 = blockIdx.x * 32;
    const int rowh = (w & 1) * 16;
    const int hbase = (w >> 1) * 64;
    const float* __restrict__ Arow = attn + (size_t)(b * 1024 + n0 + rowh + l15) * 1024;

    f32x4 acc[4];
    #pragma unroll
    for (int i = 0; i < 4; ++i) acc[i] = f32x4{0.f, 0.f, 0.f, 0.f};

    for (int c = 0; c < 8; ++c) {
        const int m0 = c * 128;
        f4 ar[8];
        #pragma unroll
        for (int ks = 0; ks < 4; ++ks) {
            ar[2 * ks]     = *(const f4*)&Arow[m0 + ks * 32 + g * 8];
            ar[2 * ks + 1] = *(const f4*)&Arow[m0 + ks * 32 + g * 8 + 4];
        }
        __syncthreads();
        #pragma unroll
        for (int i = 0; i < 16; ++i) {
            int s = t + i * 256;
            int col, ks; const unsigned short* src; char* dp;
            if (s < 2048) { col = s >> 4; ks = s & 15;
                src = &VphT[(size_t)(b * 128 + col) * 1024 + m0 + ks * 8]; dp = (char*)BH; }
            else          { int s2 = s - 2048; col = s2 >> 4; ks = s2 & 15;
                src = &VpmT[(size_t)(b * 128 + col) * 1024 + m0 + ks * 8]; dp = (char*)BM; }
            u16x8 v = *(const u16x8*)src;
            *(u16x8*)(dp + col * 256 + ((ks * 16) ^ ((col & 7) << 4))) = v;
        }
        __syncthreads();

        #pragma unroll
        for (int ks = 0; ks < 4; ++ks) {
            u16x8 ah, am;
            #pragma unroll
            for (int j = 0; j < 8; ++j) {
                float x = (j < 4) ? f4c(ar[2 * ks], j) : f4c(ar[2 * ks + 1], j - 4);
                unsigned short hb_ = f2bf(x);
                ah[j] = hb_; am[j] = f2bf(x - bf2f(hb_));
            }
            s16x8 a1 = (s16x8)ah, a2 = (s16x8)am;
            const int kbyte = (ks * 4 + g) * 16;
            #pragma unroll
            for (int cf = 0; cf < 4; ++cf) {
                int col = hbase + cf * 16 + l15;
                int off = col * 256 + (kbyte ^ ((col & 7) << 4));
                s16x8 bh = *(s16x8*)((char*)BH + off);
                s16x8 bm = *(s16x8*)((char*)BM + off);
                acc[cf] = MFMA16(a1, bh, acc[cf]);
                acc[cf] = MFMA16(a1, bm, acc[cf]);
                acc[cf] = MFMA16(a2, bh, acc[cf]);
            }
        }
    }
    #pragma unroll
    for (int cf = 0; cf < 4; ++cf)
        #pragma unroll
        for (int r = 0; r < 4; ++r)
            out[(size_t)(b * 1024 + n0 + rowh + g * 4 + r) * 128 + hbase + cf * 16 + l15] =
                acc[cf][r];
}

// ---------------- launch ----------------

extern "C" void kernel_launch(void* const* d_in, const int* in_sizes, int n_in,
                              void* d_out, int out_size, void* d_ws, size_t ws_size,
                              hipStream_t stream) {
    const float* Q   = (const float*)d_in[0];
    const float* K   = (const float*)d_in[1];
    const float* V   = (const float*)d_in[2];
    const float* Wqb = (const float*)d_in[3];
    const float* Wkb = (const float*)d_in[4];
    const float* Wqt = (const float*)d_in[5];
    const float* Wkt = (const float*)d_in[6];
    const float* Wqr = (const float*)d_in[7];
    const float* Wkr = (const float*)d_in[8];
    const float* Wv  = (const float*)d_in[9];
    const float* fw  = (const float*)d_in[10];
    const int*  mask = (const int*)d_in[11];

    unsigned short* wsu = (unsigned short*)d_ws;
    unsigned short* Wh   = wsu;              // [192][1024]
    unsigned short* Wm   = Wh + 196608;
    unsigned short* Wl3  = Wm + 196608;      // [64][1024]
    unsigned short* Wvh  = Wl3 + 65536;      // [128][1024]
    unsigned short* Wvm  = Wvh + 131072;
    unsigned short* Qt_q = Wvm + 131072;     // [8192][32] f16
    unsigned short* Kt_q = Qt_q + 262144;
    unsigned short* Qrh  = Kt_q + 262144;    // [8192][32] bf16 hi/mid
    unsigned short* Qrm  = Qrh + 262144;
    unsigned short* Krh  = Qrm + 262144;
    unsigned short* Krm  = Krh + 262144;
    unsigned short* VphT = Krm + 262144;     // [8*128][1024] bf16 hi/mid (transposed)
    unsigned short* VpmT = VphT + 1048576;
    uint_t* Qbits = (uint_t*)(VpmT + 1048576);
    uint_t* Kbits = Qbits + 8192;

    float* out  = (float*)d_out;             // [8192][128]
    float* attn = out + 1048576;             // [8192][1024]

    conv_w_kernel<<<40, 256, 0, stream>>>(Wqb, Wkb, Wqt, Wkt, Wqr, Wkr, Wv,
                                          Wh, Wm, Wl3, Wvh, Wvm);
    proj_kernel<<<512, 256, 0, stream>>>(Q, K, V, Wh, Wm, Wl3, Wvh, Wvm,
                                         Qt_q, Kt_q, Qrh, Qrm, Krh, Krm,
                                         Qbits, Kbits, VphT, VpmT);
    scores_kernel<<<dim3(64, 8), 256, 0, stream>>>(Qt_q, Kt_q, Qrh, Qrm, Krh, Krm,
                                                   Qbits, Kbits, mask, fw, attn);
    softmax_kernel<<<8192, 256, 0, stream>>>(attn);
    pv_kernel<<<dim3(32, 8), 256, 0, stream>>>(attn, VphT, VpmT, out);
}

// Round 4
// 268.495 us; speedup vs baseline: 1.1682x; 1.0384x over previous
//
#include <hip/hip_runtime.h>
#include <hip/hip_fp16.h>
#include <stdint.h>
#include <math.h>

// ProductMonoidHead — round 4: single-barrier pipelined chunks, linear-write LDS fill
// (inverse-swizzled global source), LDS-resident tropical codes in scores.
// B=8 N=M=1024 D=1024 MB=32 H=128.
// d_out = out[8192][128] f32 ++ attn[8192][1024] f32.

#define SCALE_F 0.17677669529663687f

typedef float4 f4;
typedef unsigned int uint_t;
typedef unsigned short ushort_t;
typedef __attribute__((ext_vector_type(8))) short s16x8;
typedef __attribute__((ext_vector_type(8))) unsigned short u16x8;
typedef __attribute__((ext_vector_type(4))) float f32x4;

__device__ __forceinline__ ushort_t f2bf(float x) {
    unsigned u = __float_as_uint(x);
    return (ushort_t)((u + 0x7FFFu + ((u >> 16) & 1u)) >> 16);
}
__device__ __forceinline__ float bf2f(ushort_t h) {
    return __uint_as_float(((unsigned)h) << 16);
}
__device__ __forceinline__ float f4c(const f4 v, int i) {
    return i == 0 ? v.x : (i == 1 ? v.y : (i == 2 ? v.z : v.w));
}
__device__ __forceinline__ unsigned pk_add(unsigned a, unsigned b) {
    unsigned r;
    asm("v_pk_add_f16 %0, %1, %2" : "=v"(r) : "v"(a), "v"(b));
    return r;
}
__device__ __forceinline__ unsigned pk_max(unsigned a, unsigned b) {
    unsigned r;
    asm("v_pk_max_f16 %0, %1, %2" : "=v"(r) : "v"(a), "v"(b));
    return r;
}
__device__ __forceinline__ float h2f(ushort_t u) {
    __half h;
    *reinterpret_cast<ushort_t*>(&h) = u;
    return __half2float(h);
}
__device__ __forceinline__ ushort_t f2h(float x) {
    __half h = __float2half(x);
    return *reinterpret_cast<ushort_t*>(&h);
}

#define MFMA16(a, b, c) __builtin_amdgcn_mfma_f32_16x16x32_bf16((a), (b), (c), 0, 0, 0)

// swizzled read offset (ushort index) into a [cols][64-K] level array; kq = ks*4+g in 0..7
__device__ __forceinline__ int bo(int col, int kq) {
    return col * 64 + 8 * (kq ^ (col & 7));
}
// fill: linear slot s writes ushort idx s*8; source k-element offset for that slot:
__device__ __forceinline__ int fillk(int s) {
    return 8 * ((s & 7) ^ ((s >> 3) & 7));
}

// ---------------- conv_w (unchanged) ----------------
__global__ __launch_bounds__(256)
void conv_w_kernel(const float* __restrict__ Wqb, const float* __restrict__ Wkb,
                   const float* __restrict__ Wqt, const float* __restrict__ Wkt,
                   const float* __restrict__ Wqr, const float* __restrict__ Wkr,
                   const float* __restrict__ Wv,
                   ushort_t* __restrict__ Wh, ushort_t* __restrict__ Wm,
                   ushort_t* __restrict__ Wl3,
                   ushort_t* __restrict__ Wvh, ushort_t* __restrict__ Wvm) {
    __shared__ float T[256][33];
    const int t = threadIdx.x;
    const int bid = blockIdx.x;
    const float* src;
    int kb, outRowBase, srcStride, srcColBase, side = 0;
    bool isQK, isBool;
    if (bid < 24) {
        side = bid / 12;
        int cb = (bid % 12) / 4;
        kb = bid & 3;
        const float* mats[6] = {Wqb, Wqt, Wqr, Wkb, Wkt, Wkr};
        src = mats[side * 3 + cb];
        srcStride = 32; srcColBase = 0;
        outRowBase = side * 96 + cb * 32;
        isQK = true; isBool = (cb == 0);
    } else {
        int v = bid - 24;
        int hb = v >> 2; kb = v & 3;
        src = Wv; srcStride = 128; srcColBase = hb * 32;
        outRowBase = hb * 32;
        isQK = false; isBool = false;
    }
    #pragma unroll
    for (int i = 0; i < 8; ++i) {
        int idx = t + i * 256;
        int r = idx >> 3, c4 = idx & 7;
        f4 v = *(const f4*)&src[(size_t)(kb * 256 + r) * srcStride + srcColBase + c4 * 4];
        T[r][c4 * 4 + 0] = v.x; T[r][c4 * 4 + 1] = v.y;
        T[r][c4 * 4 + 2] = v.z; T[r][c4 * 4 + 3] = v.w;
    }
    __syncthreads();
    const int col = t >> 3, kseg = t & 7;
    ushort_t* dh = isQK ? Wh : Wvh;
    ushort_t* dm = isQK ? Wm : Wvm;
    size_t obase = (size_t)(outRowBase + col) * 1024 + kb * 256 + kseg * 32;
    u16x8 ph[4], pm[4], pl[4];
    #pragma unroll
    for (int i = 0; i < 32; ++i) {
        float x = T[kseg * 32 + i][col];
        ushort_t hb_ = f2bf(x);
        float r1 = x - bf2f(hb_);
        ushort_t mb_ = f2bf(r1);
        float r2 = r1 - bf2f(mb_);
        ph[i >> 3][i & 7] = hb_;
        pm[i >> 3][i & 7] = mb_;
        pl[i >> 3][i & 7] = f2bf(r2);
    }
    #pragma unroll
    for (int i = 0; i < 4; ++i) {
        *(u16x8*)&dh[obase + i * 8] = ph[i];
        *(u16x8*)&dm[obase + i * 8] = pm[i];
    }
    if (isBool) {
        size_t lbase = (size_t)(side * 32 + col) * 1024 + kb * 256 + kseg * 32;
        #pragma unroll
        for (int i = 0; i < 4; ++i) *(u16x8*)&Wl3[lbase + i * 8] = pl[i];
    }
}

// ---------------- proj_qk: 64-row tiles, 16 chunks x 64K, 1 barrier/chunk ----------------

__global__ __launch_bounds__(256)
void proj_qk_kernel(const float* __restrict__ Q, const float* __restrict__ K,
                    const ushort_t* __restrict__ Wh, const ushort_t* __restrict__ Wm,
                    ushort_t* __restrict__ Qt_q, ushort_t* __restrict__ Kt_q,
                    ushort_t* __restrict__ Qrh, ushort_t* __restrict__ Qrm,
                    ushort_t* __restrict__ Krh, ushort_t* __restrict__ Krm,
                    uint_t* __restrict__ Qbits, uint_t* __restrict__ Kbits) {
    __shared__ ushort_t BH[2][6144];   // 96 cols x 64K
    __shared__ ushort_t BM[2][4096];   // 64 cols (bool 0-31, real 32-63)
    __shared__ uint_t sb[64];
    const int t = threadIdx.x, lane = t & 63, w = t >> 6;
    const int g = lane >> 4, l15 = lane & 15;
    const int side = blockIdx.x >> 7;
    const int row0 = (blockIdx.x & 127) * 64;
    const float* __restrict__ X = side ? K : Q;
    const float* __restrict__ Xrow = X + (size_t)(row0 + w * 16 + l15) * 1024;
    if (t < 64) sb[t] = 0;

    // fill descriptors: BH slots t,t+256,t+512 ; BM slots t,t+256
    const ushort_t* srcH[3]; int dstH[3];
    #pragma unroll
    for (int i = 0; i < 3; ++i) {
        int s = t + i * 256;
        int col = s >> 3;
        srcH[i] = Wh + (size_t)(side * 96 + col) * 1024 + fillk(s);
        dstH[i] = s * 8;
    }
    const ushort_t* srcM[2]; int dstM[2];
    #pragma unroll
    for (int i = 0; i < 2; ++i) {
        int s = t + i * 256;
        int col = s >> 3;
        int f = (col < 32) ? col : col + 32;
        srcM[i] = Wm + (size_t)(side * 96 + f) * 1024 + fillk(s);
        dstM[i] = s * 8;
    }

    f32x4 accB[2], accT[2], accR[2];
    #pragma unroll
    for (int i = 0; i < 2; ++i) {
        accB[i] = f32x4{0.f, 0.f, 0.f, 0.f};
        accT[i] = f32x4{0.f, 0.f, 0.f, 0.f};
        accR[i] = f32x4{0.f, 0.f, 0.f, 0.f};
    }

    f4 arE[4], arO[4];
    u16x8 hE[3], mE[2], hO[3], mO[2];

    auto STAGE_A = [&](int k0, f4* ar) {
        ar[0] = *(const f4*)&Xrow[k0 + g * 8];
        ar[1] = *(const f4*)&Xrow[k0 + g * 8 + 4];
        ar[2] = *(const f4*)&Xrow[k0 + 32 + g * 8];
        ar[3] = *(const f4*)&Xrow[k0 + 32 + g * 8 + 4];
    };
    auto STAGE_B = [&](int k0, u16x8* hh, u16x8* mm) {
        #pragma unroll
        for (int i = 0; i < 3; ++i) hh[i] = *(const u16x8*)(srcH[i] + k0);
        #pragma unroll
        for (int i = 0; i < 2; ++i) mm[i] = *(const u16x8*)(srcM[i] + k0);
    };
    auto WRITE_B = [&](int buf, u16x8* hh, u16x8* mm) {
        #pragma unroll
        for (int i = 0; i < 3; ++i) *(u16x8*)&BH[buf][dstH[i]] = hh[i];
        #pragma unroll
        for (int i = 0; i < 2; ++i) *(u16x8*)&BM[buf][dstM[i]] = mm[i];
    };
    auto COMPUTE = [&](int buf, f4* ar) {
        #pragma unroll
        for (int ks = 0; ks < 2; ++ks) {
            u16x8 ah, am, al;
            #pragma unroll
            for (int j = 0; j < 8; ++j) {
                float x = (j < 4) ? f4c(ar[2 * ks], j) : f4c(ar[2 * ks + 1], j - 4);
                ushort_t hb_ = f2bf(x);
                float r1 = x - bf2f(hb_);
                ushort_t mb_ = f2bf(r1);
                ah[j] = hb_; am[j] = mb_;
                al[j] = f2bf(r1 - bf2f(mb_));
            }
            s16x8 a1 = (s16x8)ah, a2 = (s16x8)am, a3 = (s16x8)al;
            const int kq = ks * 4 + g;
            #pragma unroll
            for (int cf = 0; cf < 2; ++cf) {          // bool (5-product, as R3)
                int col = cf * 16 + l15;
                s16x8 bh = *(const s16x8*)&BH[buf][bo(col, kq)];
                s16x8 bm = *(const s16x8*)&BM[buf][bo(col, kq)];
                accB[cf] = MFMA16(a1, bh, accB[cf]);
                accB[cf] = MFMA16(a1, bm, accB[cf]);
                accB[cf] = MFMA16(a2, bh, accB[cf]);
                accB[cf] = MFMA16(a2, bm, accB[cf]);
                accB[cf] = MFMA16(a3, bh, accB[cf]);
            }
            #pragma unroll
            for (int cf = 0; cf < 2; ++cf) {          // trop (1-product)
                int col = 32 + cf * 16 + l15;
                s16x8 bh = *(const s16x8*)&BH[buf][bo(col, kq)];
                accT[cf] = MFMA16(a1, bh, accT[cf]);
            }
            #pragma unroll
            for (int cf = 0; cf < 2; ++cf) {          // real (3-product)
                int colh = 64 + cf * 16 + l15;
                int colm = 32 + cf * 16 + l15;
                s16x8 bh = *(const s16x8*)&BH[buf][bo(colh, kq)];
                s16x8 bm = *(const s16x8*)&BM[buf][bo(colm, kq)];
                accR[cf] = MFMA16(a1, bh, accR[cf]);
                accR[cf] = MFMA16(a1, bm, accR[cf]);
                accR[cf] = MFMA16(a2, bh, accR[cf]);
            }
        }
    };

    // prologue
    STAGE_A(0, arE);
    STAGE_B(0, hE, mE);
    WRITE_B(0, hE, mE);
    __syncthreads();

    for (int cc = 0; cc < 8; ++cc) {
        const int kE = cc * 128;
        STAGE_A(kE + 64, arO);
        STAGE_B(kE + 64, hO, mO);
        COMPUTE(0, arE);
        WRITE_B(1, hO, mO);
        __syncthreads();
        if (cc < 7) {
            STAGE_A(kE + 128, arE);
            STAGE_B(kE + 128, hE, mE);
        }
        COMPUTE(1, arO);
        if (cc < 7) WRITE_B(0, hE, mE);
        __syncthreads();
    }

    // epilogue (identical logic to R3)
    #pragma unroll
    for (int cf = 0; cf < 2; ++cf)
        #pragma unroll
        for (int r = 0; r < 4; ++r) {
            unsigned long long bm = __ballot(accB[cf][r] > 0.f);
            if (lane == 0) {
                #pragma unroll
                for (int gg = 0; gg < 4; ++gg)
                    sb[w * 16 + gg * 4 + r] |=
                        (uint_t)((bm >> (16 * gg)) & 0xFFFFull) << (16 * cf);
            }
        }
    ushort_t* Tt = side ? Kt_q : Qt_q;
    ushort_t* Rh = side ? Krh : Qrh;
    ushort_t* Rm = side ? Krm : Qrm;
    #pragma unroll
    for (int cf = 0; cf < 2; ++cf)
        #pragma unroll
        for (int r = 0; r < 4; ++r) {
            int grow = row0 + w * 16 + g * 4 + r;
            Tt[(size_t)grow * 32 + cf * 16 + l15] = f2h(accT[cf][r]);
            float v = accR[cf][r];
            ushort_t h = f2bf(v);
            Rh[(size_t)grow * 32 + cf * 16 + l15] = h;
            Rm[(size_t)grow * 32 + cf * 16 + l15] = f2bf(v - bf2f(h));
        }
    __syncthreads();
    uint_t* Tb = side ? Kbits : Qbits;
    if (t < 64) Tb[row0 + t] = sb[t];
}

// ---------------- proj_v: 32-row tiles, 16 chunks x 64K, 1 barrier/chunk ----------------

__global__ __launch_bounds__(256)
void proj_v_kernel(const float* __restrict__ V,
                   const ushort_t* __restrict__ Wvh, const ushort_t* __restrict__ Wvm,
                   ushort_t* __restrict__ VphT, ushort_t* __restrict__ VpmT) {
    __shared__ ushort_t VH[2][8192], VM[2][8192];   // 128 cols x 64K each
    const int t = threadIdx.x, lane = t & 63, w = t >> 6;
    const int g = lane >> 4, l15 = lane & 15;
    const int tile = blockIdx.x;
    const int row0 = tile * 32;
    const int rowh = (w & 1) * 16, hbase = (w >> 1) * 64;
    const float* __restrict__ Xrow = V + (size_t)(row0 + rowh + l15) * 1024;

    const ushort_t* srcH[4]; const ushort_t* srcM[4]; int dst[4];
    #pragma unroll
    for (int i = 0; i < 4; ++i) {
        int s = t + i * 256;
        int col = s >> 3;
        srcH[i] = Wvh + (size_t)col * 1024 + fillk(s);
        srcM[i] = Wvm + (size_t)col * 1024 + fillk(s);
        dst[i] = s * 8;
    }

    f32x4 acc[4];
    #pragma unroll
    for (int i = 0; i < 4; ++i) acc[i] = f32x4{0.f, 0.f, 0.f, 0.f};

    f4 arE[4], arO[4];
    u16x8 hE[4], mE[4], hO[4], mO[4];

    auto STAGE_A = [&](int k0, f4* ar) {
        ar[0] = *(const f4*)&Xrow[k0 + g * 8];
        ar[1] = *(const f4*)&Xrow[k0 + g * 8 + 4];
        ar[2] = *(const f4*)&Xrow[k0 + 32 + g * 8];
        ar[3] = *(const f4*)&Xrow[k0 + 32 + g * 8 + 4];
    };
    auto STAGE_B = [&](int k0, u16x8* hh, u16x8* mm) {
        #pragma unroll
        for (int i = 0; i < 4; ++i) {
            hh[i] = *(const u16x8*)(srcH[i] + k0);
            mm[i] = *(const u16x8*)(srcM[i] + k0);
        }
    };
    auto WRITE_B = [&](int buf, u16x8* hh, u16x8* mm) {
        #pragma unroll
        for (int i = 0; i < 4; ++i) {
            *(u16x8*)&VH[buf][dst[i]] = hh[i];
            *(u16x8*)&VM[buf][dst[i]] = mm[i];
        }
    };
    auto COMPUTE = [&](int buf, f4* ar) {
        #pragma unroll
        for (int ks = 0; ks < 2; ++ks) {
            u16x8 ah, am;
            #pragma unroll
            for (int j = 0; j < 8; ++j) {
                float x = (j < 4) ? f4c(ar[2 * ks], j) : f4c(ar[2 * ks + 1], j - 4);
                ushort_t hb_ = f2bf(x);
                ah[j] = hb_; am[j] = f2bf(x - bf2f(hb_));
            }
            s16x8 a1 = (s16x8)ah, a2 = (s16x8)am;
            const int kq = ks * 4 + g;
            #pragma unroll
            for (int cf = 0; cf < 4; ++cf) {
                int col = hbase + cf * 16 + l15;
                s16x8 bh = *(const s16x8*)&VH[buf][bo(col, kq)];
                s16x8 bm = *(const s16x8*)&VM[buf][bo(col, kq)];
                acc[cf] = MFMA16(a1, bh, acc[cf]);
                acc[cf] = MFMA16(a1, bm, acc[cf]);
                acc[cf] = MFMA16(a2, bh, acc[cf]);
            }
        }
    };

    STAGE_A(0, arE);
    STAGE_B(0, hE, mE);
    WRITE_B(0, hE, mE);
    __syncthreads();
    for (int cc = 0; cc < 8; ++cc) {
        const int kE = cc * 128;
        STAGE_A(kE + 64, arO);
        STAGE_B(kE + 64, hO, mO);
        COMPUTE(0, arE);
        WRITE_B(1, hO, mO);
        __syncthreads();
        if (cc < 7) {
            STAGE_A(kE + 128, arE);
            STAGE_B(kE + 128, hE, mE);
        }
        COMPUTE(1, arO);
        if (cc < 7) WRITE_B(0, hE, mE);
        __syncthreads();
    }

    // epilogue: direct transposed store (4 consecutive m per lane), as R3
    const int b = tile >> 5;
    const int mbase = (tile & 31) * 32 + rowh + g * 4;
    #pragma unroll
    for (int cf = 0; cf < 4; ++cf) {
        int colh = hbase + cf * 16 + l15;
        float v0 = acc[cf][0], v1 = acc[cf][1], v2 = acc[cf][2], v3 = acc[cf][3];
        ushort_t h0 = f2bf(v0), h1 = f2bf(v1), h2_ = f2bf(v2), h3 = f2bf(v3);
        ushort4 hv = make_ushort4(h0, h1, h2_, h3);
        ushort4 mv = make_ushort4(f2bf(v0 - bf2f(h0)), f2bf(v1 - bf2f(h1)),
                                  f2bf(v2 - bf2f(h2_)), f2bf(v3 - bf2f(h3)));
        size_t ob = (size_t)(b * 128 + colh) * 1024 + mbase;
        *(ushort4*)&VphT[ob] = hv;
        *(ushort4*)&VpmT[ob] = mv;
    }
}

// ---------------- scores: LDS-resident tropical K-codes, raw scores out ----------------

__global__ __launch_bounds__(256)
void scores_kernel(const ushort_t* __restrict__ Qt_q, const ushort_t* __restrict__ Kt_q,
                   const ushort_t* __restrict__ Qrh, const ushort_t* __restrict__ Qrm,
                   const ushort_t* __restrict__ Krh, const ushort_t* __restrict__ Krm,
                   const uint_t* __restrict__ Qbits, const uint_t* __restrict__ Kbits,
                   const float* __restrict__ fw, float* __restrict__ attn) {
    __shared__ uint_t KtT[4][1024][4];   // 64 KB: [j4][m][j&3]
    const int t = threadIdx.x, lane = t & 63, w = t >> 6;
    const int g = lane >> 4, l15 = lane & 15;
    const int b = blockIdx.y, n0 = blockIdx.x * 16;
    const int rowA = b * 1024 + n0;

    #pragma unroll
    for (int i = 0; i < 16; ++i) {
        int j4 = i >> 2, row = t + (i & 3) * 256;
        u16x8 v = *(const u16x8*)&Kt_q[(size_t)(b * 1024 + row) * 32 + j4 * 8];
        *(u16x8*)&KtT[j4][row][0] = v;
    }

    s16x8 qrh = *(const s16x8*)&Qrh[(size_t)(rowA + l15) * 32 + g * 8];
    s16x8 qrm = *(const s16x8*)&Qrm[(size_t)(rowA + l15) * 32 + g * 8];
    uint_t qt[4][16], qb[4];
    #pragma unroll
    for (int r = 0; r < 4; ++r) {
        const uint_t* p = (const uint_t*)&Qt_q[(size_t)(rowA + 4 * g + r) * 32];
        #pragma unroll
        for (int j = 0; j < 16; ++j) qt[r][j] = p[j];
        qb[r] = Qbits[rowA + 4 * g + r];
    }
    const float f0 = fw[0], f1 = fw[1], f2 = fw[2];
    const float fm = fmaxf(f0, fmaxf(f1, f2));
    const float e0 = __expf(f0 - fm), e1 = __expf(f1 - fm), e2 = __expf(f2 - fm);
    const float wi = 1.f / (e0 + e1 + e2);
    const float w0 = e0 * wi, w1 = e1 * wi, w2 = e2 * wi;
    __syncthreads();

    for (int i = 0; i < 16; ++i) {
        const int m0 = (w + 4 * i) * 16;
        const int mrow = b * 1024 + m0;
        s16x8 krh = *(const s16x8*)&Krh[(size_t)(mrow + l15) * 32 + g * 8];
        s16x8 krm = *(const s16x8*)&Krm[(size_t)(mrow + l15) * 32 + g * 8];
        uint_t kb = Kbits[mrow + l15];

        f32x4 rc = f32x4{0.f, 0.f, 0.f, 0.f};
        rc = MFMA16(qrh, krh, rc);
        rc = MFMA16(qrh, krm, rc);
        rc = MFMA16(qrm, krh, rc);

        const int m = m0 + l15;
        uint_t kk[16];
        uint4 k0v = *(const uint4*)&KtT[0][m][0];
        uint4 k1v = *(const uint4*)&KtT[1][m][0];
        uint4 k2v = *(const uint4*)&KtT[2][m][0];
        uint4 k3v = *(const uint4*)&KtT[3][m][0];
        kk[0] = k0v.x; kk[1] = k0v.y; kk[2] = k0v.z; kk[3] = k0v.w;
        kk[4] = k1v.x; kk[5] = k1v.y; kk[6] = k1v.z; kk[7] = k1v.w;
        kk[8] = k2v.x; kk[9] = k2v.y; kk[10] = k2v.z; kk[11] = k2v.w;
        kk[12] = k3v.x; kk[13] = k3v.y; kk[14] = k3v.z; kk[15] = k3v.w;

        float trop[4];
        #pragma unroll
        for (int r = 0; r < 4; ++r) {
            unsigned a = pk_add(qt[r][0], kk[0]);
            #pragma unroll
            for (int j = 1; j < 16; ++j)
                a = pk_max(a, pk_add(qt[r][j], kk[j]));
            trop[r] = fmaxf(h2f((ushort_t)(a & 0xFFFF)), h2f((ushort_t)(a >> 16)));
        }
        #pragma unroll
        for (int r = 0; r < 4; ++r) {
            float cnt = (float)(32 - __popc(qb[r] ^ kb));
            attn[(size_t)(rowA + 4 * g + r) * 1024 + m] =
                (w0 * cnt + w1 * trop[r] + w2 * rc[r]) * SCALE_F;
        }
    }
}

// ---------------- softmax: masked, in place (R2-proven) ----------------

__global__ __launch_bounds__(256)
void softmax_kernel(float* __restrict__ attn, const int* __restrict__ mask) {
    const int row = blockIdx.x;
    const int t = threadIdx.x;
    const f4  s4 = ((const f4*)attn)[(size_t)row * 256 + t];
    const int4 m4 = ((const int4*)mask)[(size_t)row * 256 + t];
    const float v0 = m4.x ? s4.x : -INFINITY;
    const float v1 = m4.y ? s4.y : -INFINITY;
    const float v2 = m4.z ? s4.z : -INFINITY;
    const float v3 = m4.w ? s4.w : -INFINITY;

    float tm = fmaxf(fmaxf(v0, v1), fmaxf(v2, v3));
    #pragma unroll
    for (int off = 32; off >= 1; off >>= 1) tm = fmaxf(tm, __shfl_xor(tm, off, 64));
    __shared__ float rmax[4], rsum[4];
    if ((t & 63) == 0) rmax[t >> 6] = tm;
    __syncthreads();
    const float gm = fmaxf(fmaxf(rmax[0], rmax[1]), fmaxf(rmax[2], rmax[3]));

    const float x0 = m4.x ? __expf(v0 - gm) : 0.f;
    const float x1 = m4.y ? __expf(v1 - gm) : 0.f;
    const float x2 = m4.z ? __expf(v2 - gm) : 0.f;
    const float x3 = m4.w ? __expf(v3 - gm) : 0.f;
    float ts = (x0 + x1) + (x2 + x3);
    #pragma unroll
    for (int off = 32; off >= 1; off >>= 1) ts += __shfl_xor(ts, off, 64);
    if ((t & 63) == 0) rsum[t >> 6] = ts;
    __syncthreads();
    const float inv = 1.f / ((rsum[0] + rsum[1]) + (rsum[2] + rsum[3]));

    ((f4*)attn)[(size_t)row * 256 + t] = make_float4(x0 * inv, x1 * inv, x2 * inv, x3 * inv);
}

// ---------------- pv: 32-row tiles, 16 chunks x 64m, 1 barrier/chunk ----------------

__global__ __launch_bounds__(256)
void pv_kernel(const float* __restrict__ attn,
               const ushort_t* __restrict__ VphT, const ushort_t* __restrict__ VpmT,
               float* __restrict__ out) {
    __shared__ ushort_t VH[2][8192], VM[2][8192];   // 128 cols x 64m
    const int t = threadIdx.x, lane = t & 63, w = t >> 6;
    const int g = lane >> 4, l15 = lane & 15;
    const int b = blockIdx.x >> 5;
    const int n0 = (blockIdx.x & 31) * 32;
    const int rowh = (w & 1) * 16, hbase = (w >> 1) * 64;
    const float* __restrict__ Arow = attn + (size_t)(b * 1024 + n0 + rowh + l15) * 1024;

    const ushort_t* srcH[4]; const ushort_t* srcM[4]; int dst[4];
    #pragma unroll
    for (int i = 0; i < 4; ++i) {
        int s = t + i * 256;
        int col = s >> 3;
        srcH[i] = VphT + (size_t)(b * 128 + col) * 1024 + fillk(s);
        srcM[i] = VpmT + (size_t)(b * 128 + col) * 1024 + fillk(s);
        dst[i] = s * 8;
    }

    f32x4 acc[4];
    #pragma unroll
    for (int i = 0; i < 4; ++i) acc[i] = f32x4{0.f, 0.f, 0.f, 0.f};

    f4 arE[4], arO[4];
    u16x8 hE[4], mE[4], hO[4], mO[4];

    auto STAGE_A = [&](int k0, f4* ar) {
        ar[0] = *(const f4*)&Arow[k0 + g * 8];
        ar[1] = *(const f4*)&Arow[k0 + g * 8 + 4];
        ar[2] = *(const f4*)&Arow[k0 + 32 + g * 8];
        ar[3] = *(const f4*)&Arow[k0 + 32 + g * 8 + 4];
    };
    auto STAGE_B = [&](int k0, u16x8* hh, u16x8* mm) {
        #pragma unroll
        for (int i = 0; i < 4; ++i) {
            hh[i] = *(const u16x8*)(srcH[i] + k0);
            mm[i] = *(const u16x8*)(srcM[i] + k0);
        }
    };
    auto WRITE_B = [&](int buf, u16x8* hh, u16x8* mm) {
        #pragma unroll
        for (int i = 0; i < 4; ++i) {
            *(u16x8*)&VH[buf][dst[i]] = hh[i];
            *(u16x8*)&VM[buf][dst[i]] = mm[i];
        }
    };
    auto COMPUTE = [&](int buf, f4* ar) {
        #pragma unroll
        for (int ks = 0; ks < 2; ++ks) {
            u16x8 ah, am;
            #pragma unroll
            for (int j = 0; j < 8; ++j) {
                float x = (j < 4) ? f4c(ar[2 * ks], j) : f4c(ar[2 * ks + 1], j - 4);
                ushort_t hb_ = f2bf(x);
                ah[j] = hb_; am[j] = f2bf(x - bf2f(hb_));
            }
            s16x8 a1 = (s16x8)ah, a2 = (s16x8)am;
            const int kq = ks * 4 + g;
            #pragma unroll
            for (int cf = 0; cf < 4; ++cf) {
                int col = hbase + cf * 16 + l15;
                s16x8 bh = *(const s16x8*)&VH[buf][bo(col, kq)];
                s16x8 bm = *(const s16x8*)&VM[buf][bo(col, kq)];
                acc[cf] = MFMA16(a1, bh, acc[cf]);
                acc[cf] = MFMA16(a1, bm, acc[cf]);
                acc[cf] = MFMA16(a2, bh, acc[cf]);
            }
        }
    };

    STAGE_A(0, arE);
    STAGE_B(0, hE, mE);
    WRITE_B(0, hE, mE);
    __syncthreads();
    for (int cc = 0; cc < 8; ++cc) {
        const int kE = cc * 128;
        STAGE_A(kE + 64, arO);
        STAGE_B(kE + 64, hO, mO);
        COMPUTE(0, arE);
        WRITE_B(1, hO, mO);
        __syncthreads();
        if (cc < 7) {
            STAGE_A(kE + 128, arE);
            STAGE_B(kE + 128, hE, mE);
        }
        COMPUTE(1, arO);
        if (cc < 7) WRITE_B(0, hE, mE);
        __syncthreads();
    }

    #pragma unroll
    for (int cf = 0; cf < 4; ++cf)
        #pragma unroll
        for (int r = 0; r < 4; ++r)
            out[(size_t)(b * 1024 + n0 + rowh + g * 4 + r) * 128 + hbase + cf * 16 + l15] =
                acc[cf][r];
}

// ---------------- launch ----------------

extern "C" void kernel_launch(void* const* d_in, const int* in_sizes, int n_in,
                              void* d_out, int out_size, void* d_ws, size_t ws_size,
                              hipStream_t stream) {
    const float* Q   = (const float*)d_in[0];
    const float* K   = (const float*)d_in[1];
    const float* V   = (const float*)d_in[2];
    const float* Wqb = (const float*)d_in[3];
    const float* Wkb = (const float*)d_in[4];
    const float* Wqt = (const float*)d_in[5];
    const float* Wkt = (const float*)d_in[6];
    const float* Wqr = (const float*)d_in[7];
    const float* Wkr = (const float*)d_in[8];
    const float* Wv  = (const float*)d_in[9];
    const float* fw  = (const float*)d_in[10];
    const int*  mask = (const int*)d_in[11];

    ushort_t* wsu = (ushort_t*)d_ws;
    ushort_t* Wh   = wsu;              // [192][1024]
    ushort_t* Wm   = Wh + 196608;
    ushort_t* Wl3  = Wm + 196608;      // [64][1024] (written by conv_w, unused downstream)
    ushort_t* Wvh  = Wl3 + 65536;      // [128][1024]
    ushort_t* Wvm  = Wvh + 131072;
    ushort_t* Qt_q = Wvm + 131072;     // [8192][32] f16
    ushort_t* Kt_q = Qt_q + 262144;
    ushort_t* Qrh  = Kt_q + 262144;    // [8192][32] bf16 hi/mid
    ushort_t* Qrm  = Qrh + 262144;
    ushort_t* Krh  = Qrm + 262144;
    ushort_t* Krm  = Krh + 262144;
    ushort_t* VphT = Krm + 262144;     // [8*128][1024] bf16 hi/mid (transposed)
    ushort_t* VpmT = VphT + 1048576;
    uint_t* Qbits = (uint_t*)(VpmT + 1048576);
    uint_t* Kbits = Qbits + 8192;

    float* out  = (float*)d_out;       // [8192][128]
    float* attn = out + 1048576;       // [8192][1024]

    conv_w_kernel<<<40, 256, 0, stream>>>(Wqb, Wkb, Wqt, Wkt, Wqr, Wkr, Wv,
                                          Wh, Wm, Wl3, Wvh, Wvm);
    proj_qk_kernel<<<256, 256, 0, stream>>>(Q, K, Wh, Wm,
                                            Qt_q, Kt_q, Qrh, Qrm, Krh, Krm, Qbits, Kbits);
    proj_v_kernel<<<256, 256, 0, stream>>>(V, Wvh, Wvm, VphT, VpmT);
    scores_kernel<<<dim3(64, 8), 256, 0, stream>>>(Qt_q, Kt_q, Qrh, Qrm, Krh, Krm,
                                                   Qbits, Kbits, fw, attn);
    softmax_kernel<<<8192, 256, 0, stream>>>(attn, mask);
    pv_kernel<<<256, 256, 0, stream>>>(attn, VphT, VpmT, out);
}

// Round 6
// 267.777 us; speedup vs baseline: 1.1714x; 1.0027x over previous
//
#include <hip/hip_runtime.h>
#include <hip/hip_fp16.h>
#include <stdint.h>
#include <math.h>

// ProductMonoidHead — round 6 (= R5 resubmit + XCD-local fused grid).
// B=8 N=M=1024 D=1024 MB=32 H=128.
// d_out = out[8192][128] f32 ++ attn[8192][1024] f32.

#define SCALE_F 0.17677669529663687f

typedef float4 f4;
typedef unsigned int uint_t;
typedef unsigned short ushort_t;
typedef __attribute__((ext_vector_type(8))) short s16x8;
typedef __attribute__((ext_vector_type(8))) unsigned short u16x8;
typedef __attribute__((ext_vector_type(4))) float f32x4;

__device__ __forceinline__ ushort_t f2bf(float x) {
    unsigned u = __float_as_uint(x);
    return (ushort_t)((u + 0x7FFFu + ((u >> 16) & 1u)) >> 16);
}
__device__ __forceinline__ float bf2f(ushort_t h) {
    return __uint_as_float(((unsigned)h) << 16);
}
__device__ __forceinline__ float f4c(const f4 v, int i) {
    return i == 0 ? v.x : (i == 1 ? v.y : (i == 2 ? v.z : v.w));
}
__device__ __forceinline__ unsigned pk_add(unsigned a, unsigned b) {
    unsigned r;
    asm("v_pk_add_f16 %0, %1, %2" : "=v"(r) : "v"(a), "v"(b));
    return r;
}
__device__ __forceinline__ unsigned pk_max(unsigned a, unsigned b) {
    unsigned r;
    asm("v_pk_max_f16 %0, %1, %2" : "=v"(r) : "v"(a), "v"(b));
    return r;
}
__device__ __forceinline__ float h2f(ushort_t u) {
    __half h;
    *reinterpret_cast<ushort_t*>(&h) = u;
    return __half2float(h);
}
__device__ __forceinline__ ushort_t f2h(float x) {
    __half h = __float2half(x);
    return *reinterpret_cast<ushort_t*>(&h);
}

#define MFMA16(a, b, c) __builtin_amdgcn_mfma_f32_16x16x32_bf16((a), (b), (c), 0, 0, 0)

// swizzled read offset (ushort index) into a [cols][64-K] level array; kq in 0..7
__device__ __forceinline__ int bo(int col, int kq) {
    return col * 64 + 8 * (kq ^ (col & 7));
}
// fill: linear slot s writes ushort idx s*8; inverse-swizzled source k-offset:
__device__ __forceinline__ int fillk(int s) {
    return 8 * ((s & 7) ^ ((s >> 3) & 7));
}

// ---------------- conv_w (unchanged) ----------------
__global__ __launch_bounds__(256)
void conv_w_kernel(const float* __restrict__ Wqb, const float* __restrict__ Wkb,
                   const float* __restrict__ Wqt, const float* __restrict__ Wkt,
                   const float* __restrict__ Wqr, const float* __restrict__ Wkr,
                   const float* __restrict__ Wv,
                   ushort_t* __restrict__ Wh, ushort_t* __restrict__ Wm,
                   ushort_t* __restrict__ Wl3,
                   ushort_t* __restrict__ Wvh, ushort_t* __restrict__ Wvm) {
    __shared__ float T[256][33];
    const int t = threadIdx.x;
    const int bid = blockIdx.x;
    const float* src;
    int kb, outRowBase, srcStride, srcColBase, side = 0;
    bool isQK, isBool;
    if (bid < 24) {
        side = bid / 12;
        int cb = (bid % 12) / 4;
        kb = bid & 3;
        const float* mats[6] = {Wqb, Wqt, Wqr, Wkb, Wkt, Wkr};
        src = mats[side * 3 + cb];
        srcStride = 32; srcColBase = 0;
        outRowBase = side * 96 + cb * 32;
        isQK = true; isBool = (cb == 0);
    } else {
        int v = bid - 24;
        int hb = v >> 2; kb = v & 3;
        src = Wv; srcStride = 128; srcColBase = hb * 32;
        outRowBase = hb * 32;
        isQK = false; isBool = false;
    }
    #pragma unroll
    for (int i = 0; i < 8; ++i) {
        int idx = t + i * 256;
        int r = idx >> 3, c4 = idx & 7;
        f4 v = *(const f4*)&src[(size_t)(kb * 256 + r) * srcStride + srcColBase + c4 * 4];
        T[r][c4 * 4 + 0] = v.x; T[r][c4 * 4 + 1] = v.y;
        T[r][c4 * 4 + 2] = v.z; T[r][c4 * 4 + 3] = v.w;
    }
    __syncthreads();
    const int col = t >> 3, kseg = t & 7;
    ushort_t* dh = isQK ? Wh : Wvh;
    ushort_t* dm = isQK ? Wm : Wvm;
    size_t obase = (size_t)(outRowBase + col) * 1024 + kb * 256 + kseg * 32;
    u16x8 ph[4], pm[4], pl[4];
    #pragma unroll
    for (int i = 0; i < 32; ++i) {
        float x = T[kseg * 32 + i][col];
        ushort_t hb_ = f2bf(x);
        float r1 = x - bf2f(hb_);
        ushort_t mb_ = f2bf(r1);
        float r2 = r1 - bf2f(mb_);
        ph[i >> 3][i & 7] = hb_;
        pm[i >> 3][i & 7] = mb_;
        pl[i >> 3][i & 7] = f2bf(r2);
    }
    #pragma unroll
    for (int i = 0; i < 4; ++i) {
        *(u16x8*)&dh[obase + i * 8] = ph[i];
        *(u16x8*)&dm[obase + i * 8] = pm[i];
    }
    if (isBool) {
        size_t lbase = (size_t)(side * 32 + col) * 1024 + kb * 256 + kseg * 32;
        #pragma unroll
        for (int i = 0; i < 4; ++i) *(u16x8*)&Wl3[lbase + i * 8] = pl[i];
    }
}

// ---------------- proj_qk: 32-row tiles x 512 blocks, wave = (rowgrp, monoid-half) ----------------

__global__ __launch_bounds__(256)
void proj_qk_kernel(const float* __restrict__ Q, const float* __restrict__ K,
                    const ushort_t* __restrict__ Wh, const ushort_t* __restrict__ Wm,
                    ushort_t* __restrict__ Qt_q, ushort_t* __restrict__ Kt_q,
                    ushort_t* __restrict__ Qrh, ushort_t* __restrict__ Qrm,
                    ushort_t* __restrict__ Krh, ushort_t* __restrict__ Krm,
                    uint_t* __restrict__ Qbits, uint_t* __restrict__ Kbits) {
    __shared__ ushort_t BH[2][6144];   // 96 cols x 64K
    __shared__ ushort_t BM[2][4096];   // 64 cols (bool-mid 0-31, real-mid 32-63)
    __shared__ uint_t sb[32];
    const int t = threadIdx.x, lane = t & 63, w = t >> 6;
    const int g = lane >> 4, l15 = lane & 15;
    const int side = blockIdx.x >> 8;
    const int tile = blockIdx.x & 255;
    const int row0 = tile * 32;
    const int rg = w >> 1;             // row group (16 rows)
    const int ch = w & 1;              // 0 = bool waves, 1 = trop+real waves
    const float* __restrict__ X = side ? K : Q;
    const float* __restrict__ Xrow = X + (size_t)(row0 + rg * 16 + l15) * 1024;
    if (t < 32) sb[t] = 0;

    const ushort_t* srcH[3]; int dstH[3];
    #pragma unroll
    for (int i = 0; i < 3; ++i) {
        int s = t + i * 256;
        int col = s >> 3;
        srcH[i] = Wh + (size_t)(side * 96 + col) * 1024 + fillk(s);
        dstH[i] = s * 8;
    }
    const ushort_t* srcM[2]; int dstM[2];
    #pragma unroll
    for (int i = 0; i < 2; ++i) {
        int s = t + i * 256;
        int col = s >> 3;
        int f = (col < 32) ? col : col + 32;
        srcM[i] = Wm + (size_t)(side * 96 + f) * 1024 + fillk(s);
        dstM[i] = s * 8;
    }

    f32x4 accB[2], accT[2], accR[2];
    #pragma unroll
    for (int i = 0; i < 2; ++i) {
        accB[i] = f32x4{0.f, 0.f, 0.f, 0.f};
        accT[i] = f32x4{0.f, 0.f, 0.f, 0.f};
        accR[i] = f32x4{0.f, 0.f, 0.f, 0.f};
    }

    f4 arE[4], arO[4];
    u16x8 hE[3], mE[2], hO[3], mO[2];

    auto STAGE_A = [&](int k0, f4* ar) {
        ar[0] = *(const f4*)&Xrow[k0 + g * 8];
        ar[1] = *(const f4*)&Xrow[k0 + g * 8 + 4];
        ar[2] = *(const f4*)&Xrow[k0 + 32 + g * 8];
        ar[3] = *(const f4*)&Xrow[k0 + 32 + g * 8 + 4];
    };
    auto STAGE_B = [&](int k0, u16x8* hh, u16x8* mm) {
        #pragma unroll
        for (int i = 0; i < 3; ++i) hh[i] = *(const u16x8*)(srcH[i] + k0);
        #pragma unroll
        for (int i = 0; i < 2; ++i) mm[i] = *(const u16x8*)(srcM[i] + k0);
    };
    auto WRITE_B = [&](int buf, u16x8* hh, u16x8* mm) {
        #pragma unroll
        for (int i = 0; i < 3; ++i) *(u16x8*)&BH[buf][dstH[i]] = hh[i];
        #pragma unroll
        for (int i = 0; i < 2; ++i) *(u16x8*)&BM[buf][dstM[i]] = mm[i];
    };
    auto COMPUTE = [&](int buf, f4* ar) {
        #pragma unroll
        for (int ks = 0; ks < 2; ++ks) {
            u16x8 ah, am, al;
            #pragma unroll
            for (int j = 0; j < 8; ++j) {
                float x = (j < 4) ? f4c(ar[2 * ks], j) : f4c(ar[2 * ks + 1], j - 4);
                ushort_t hb_ = f2bf(x);
                float r1 = x - bf2f(hb_);
                ushort_t mb_ = f2bf(r1);
                ah[j] = hb_; am[j] = mb_;
                al[j] = f2bf(r1 - bf2f(mb_));
            }
            s16x8 a1 = (s16x8)ah, a2 = (s16x8)am;
            const int kq = ks * 4 + g;
            if (ch == 0) {                         // bool (5-product)
                s16x8 a3 = (s16x8)al;
                #pragma unroll
                for (int cf = 0; cf < 2; ++cf) {
                    int col = cf * 16 + l15;
                    s16x8 bh = *(const s16x8*)&BH[buf][bo(col, kq)];
                    s16x8 bm = *(const s16x8*)&BM[buf][bo(col, kq)];
                    accB[cf] = MFMA16(a1, bh, accB[cf]);
                    accB[cf] = MFMA16(a1, bm, accB[cf]);
                    accB[cf] = MFMA16(a2, bh, accB[cf]);
                    accB[cf] = MFMA16(a2, bm, accB[cf]);
                    accB[cf] = MFMA16(a3, bh, accB[cf]);
                }
            } else {                               // trop (1) + real (3)
                #pragma unroll
                for (int cf = 0; cf < 2; ++cf) {
                    int col = 32 + cf * 16 + l15;
                    s16x8 bh = *(const s16x8*)&BH[buf][bo(col, kq)];
                    accT[cf] = MFMA16(a1, bh, accT[cf]);
                }
                #pragma unroll
                for (int cf = 0; cf < 2; ++cf) {
                    int colh = 64 + cf * 16 + l15;
                    int colm = 32 + cf * 16 + l15;
                    s16x8 bh = *(const s16x8*)&BH[buf][bo(colh, kq)];
                    s16x8 bm = *(const s16x8*)&BM[buf][bo(colm, kq)];
                    accR[cf] = MFMA16(a1, bh, accR[cf]);
                    accR[cf] = MFMA16(a1, bm, accR[cf]);
                    accR[cf] = MFMA16(a2, bh, accR[cf]);
                }
            }
        }
    };

    STAGE_A(0, arE);
    STAGE_B(0, hE, mE);
    WRITE_B(0, hE, mE);
    __syncthreads();
    for (int cc = 0; cc < 8; ++cc) {
        const int kE = cc * 128;
        STAGE_A(kE + 64, arO);
        STAGE_B(kE + 64, hO, mO);
        COMPUTE(0, arE);
        WRITE_B(1, hO, mO);
        __syncthreads();
        if (cc < 7) {
            STAGE_A(kE + 128, arE);
            STAGE_B(kE + 128, hE, mE);
        }
        COMPUTE(1, arO);
        if (cc < 7) WRITE_B(0, hE, mE);
        __syncthreads();
    }

    if (ch == 0) {
        #pragma unroll
        for (int cf = 0; cf < 2; ++cf)
            #pragma unroll
            for (int r = 0; r < 4; ++r) {
                unsigned long long bm = __ballot(accB[cf][r] > 0.f);
                if (lane == 0) {
                    #pragma unroll
                    for (int gg = 0; gg < 4; ++gg)
                        sb[rg * 16 + gg * 4 + r] |=
                            (uint_t)((bm >> (16 * gg)) & 0xFFFFull) << (16 * cf);
                }
            }
    } else {
        ushort_t* Tt = side ? Kt_q : Qt_q;
        ushort_t* Rh = side ? Krh : Qrh;
        ushort_t* Rm = side ? Krm : Qrm;
        #pragma unroll
        for (int cf = 0; cf < 2; ++cf)
            #pragma unroll
            for (int r = 0; r < 4; ++r) {
                int grow = row0 + rg * 16 + g * 4 + r;
                Tt[(size_t)grow * 32 + cf * 16 + l15] = f2h(accT[cf][r]);
                float v = accR[cf][r];
                ushort_t h = f2bf(v);
                Rh[(size_t)grow * 32 + cf * 16 + l15] = h;
                Rm[(size_t)grow * 32 + cf * 16 + l15] = f2bf(v - bf2f(h));
            }
    }
    __syncthreads();
    uint_t* Tb = side ? Kbits : Qbits;
    if (t < 32) Tb[row0 + t] = sb[t];
}

// ---------------- proj_v: 16-row tiles x 512 blocks, wave = 32 h ----------------

__global__ __launch_bounds__(256)
void proj_v_kernel(const float* __restrict__ V,
                   const ushort_t* __restrict__ Wvh, const ushort_t* __restrict__ Wvm,
                   ushort_t* __restrict__ VphT, ushort_t* __restrict__ VpmT) {
    __shared__ ushort_t VH[2][8192], VM[2][8192];
    const int t = threadIdx.x, lane = t & 63, w = t >> 6;
    const int g = lane >> 4, l15 = lane & 15;
    const int tile = blockIdx.x;
    const int row0 = tile * 16;
    const int hbase = w * 32;
    const float* __restrict__ Xrow = V + (size_t)(row0 + l15) * 1024;

    const ushort_t* srcH[4]; const ushort_t* srcM[4]; int dst[4];
    #pragma unroll
    for (int i = 0; i < 4; ++i) {
        int s = t + i * 256;
        int col = s >> 3;
        srcH[i] = Wvh + (size_t)col * 1024 + fillk(s);
        srcM[i] = Wvm + (size_t)col * 1024 + fillk(s);
        dst[i] = s * 8;
    }

    f32x4 acc[2];
    acc[0] = f32x4{0.f, 0.f, 0.f, 0.f};
    acc[1] = f32x4{0.f, 0.f, 0.f, 0.f};

    f4 arE[4], arO[4];
    u16x8 hE[4], mE[4], hO[4], mO[4];

    auto STAGE_A = [&](int k0, f4* ar) {
        ar[0] = *(const f4*)&Xrow[k0 + g * 8];
        ar[1] = *(const f4*)&Xrow[k0 + g * 8 + 4];
        ar[2] = *(const f4*)&Xrow[k0 + 32 + g * 8];
        ar[3] = *(const f4*)&Xrow[k0 + 32 + g * 8 + 4];
    };
    auto STAGE_B = [&](int k0, u16x8* hh, u16x8* mm) {
        #pragma unroll
        for (int i = 0; i < 4; ++i) {
            hh[i] = *(const u16x8*)(srcH[i] + k0);
            mm[i] = *(const u16x8*)(srcM[i] + k0);
        }
    };
    auto WRITE_B = [&](int buf, u16x8* hh, u16x8* mm) {
        #pragma unroll
        for (int i = 0; i < 4; ++i) {
            *(u16x8*)&VH[buf][dst[i]] = hh[i];
            *(u16x8*)&VM[buf][dst[i]] = mm[i];
        }
    };
    auto COMPUTE = [&](int buf, f4* ar) {
        #pragma unroll
        for (int ks = 0; ks < 2; ++ks) {
            u16x8 ah, am;
            #pragma unroll
            for (int j = 0; j < 8; ++j) {
                float x = (j < 4) ? f4c(ar[2 * ks], j) : f4c(ar[2 * ks + 1], j - 4);
                ushort_t hb_ = f2bf(x);
                ah[j] = hb_; am[j] = f2bf(x - bf2f(hb_));
            }
            s16x8 a1 = (s16x8)ah, a2 = (s16x8)am;
            const int kq = ks * 4 + g;
            #pragma unroll
            for (int cf = 0; cf < 2; ++cf) {
                int col = hbase + cf * 16 + l15;
                s16x8 bh = *(const s16x8*)&VH[buf][bo(col, kq)];
                s16x8 bm = *(const s16x8*)&VM[buf][bo(col, kq)];
                acc[cf] = MFMA16(a1, bh, acc[cf]);
                acc[cf] = MFMA16(a1, bm, acc[cf]);
                acc[cf] = MFMA16(a2, bh, acc[cf]);
            }
        }
    };

    STAGE_A(0, arE);
    STAGE_B(0, hE, mE);
    WRITE_B(0, hE, mE);
    __syncthreads();
    for (int cc = 0; cc < 8; ++cc) {
        const int kE = cc * 128;
        STAGE_A(kE + 64, arO);
        STAGE_B(kE + 64, hO, mO);
        COMPUTE(0, arE);
        WRITE_B(1, hO, mO);
        __syncthreads();
        if (cc < 7) {
            STAGE_A(kE + 128, arE);
            STAGE_B(kE + 128, hE, mE);
        }
        COMPUTE(1, arO);
        if (cc < 7) WRITE_B(0, hE, mE);
        __syncthreads();
    }

    const int b = tile >> 6;
    const int mb = (tile & 63) * 16 + g * 4;
    #pragma unroll
    for (int cf = 0; cf < 2; ++cf) {
        int colh = hbase + cf * 16 + l15;
        float v0 = acc[cf][0], v1 = acc[cf][1], v2 = acc[cf][2], v3 = acc[cf][3];
        ushort_t h0 = f2bf(v0), h1 = f2bf(v1), h2_ = f2bf(v2), h3 = f2bf(v3);
        ushort4 hv = make_ushort4(h0, h1, h2_, h3);
        ushort4 mv = make_ushort4(f2bf(v0 - bf2f(h0)), f2bf(v1 - bf2f(h1)),
                                  f2bf(v2 - bf2f(h2_)), f2bf(v3 - bf2f(h3)));
        size_t ob = (size_t)(b * 128 + colh) * 1024 + mb;
        *(ushort4*)&VphT[ob] = hv;
        *(ushort4*)&VpmT[ob] = mv;
    }
}

// ---------------- fused: scores -> softmax -> attn write + PV, 16 rows/block ----------------
// grid: 512 flat blocks; b = bid & 7 so all blocks of a batch land on one XCD
// (linearized dispatch round-robins XCDs) -> that XCD's V panel + K codes stay L2-hot.

#define SW 1036   // S row stride in uints (bank-skewed)

__global__ __launch_bounds__(256)
void fused_attn_kernel(const ushort_t* __restrict__ Qt_q, const ushort_t* __restrict__ Kt_q,
                       const ushort_t* __restrict__ Qrh, const ushort_t* __restrict__ Qrm,
                       const ushort_t* __restrict__ Krh, const ushort_t* __restrict__ Krm,
                       const uint_t* __restrict__ Qbits, const uint_t* __restrict__ Kbits,
                       const ushort_t* __restrict__ VphT, const ushort_t* __restrict__ VpmT,
                       const int* __restrict__ mask, const float* __restrict__ fw,
                       float* __restrict__ attn, float* __restrict__ out) {
    __shared__ uint_t S[16][SW];       // scores f32, later P packed (hi|mid<<16)
    __shared__ float rmaxS[16], rinvS[16];
    const int t = threadIdx.x, lane = t & 63, w = t >> 6;
    const int g = lane >> 4, l15 = lane & 15;
    const int bid = blockIdx.x;
    const int b = bid & 7, n0 = (bid >> 3) * 16;   // XCD-local batch mapping
    const int rowA = b * 1024 + n0;

    // ---- per-thread Q operands ----
    s16x8 qrh = *(const s16x8*)&Qrh[(size_t)(rowA + l15) * 32 + g * 8];
    s16x8 qrm = *(const s16x8*)&Qrm[(size_t)(rowA + l15) * 32 + g * 8];
    uint_t qt[4][16], qb[4];
    #pragma unroll
    for (int r = 0; r < 4; ++r) {
        const uint_t* p = (const uint_t*)&Qt_q[(size_t)(rowA + 4 * g + r) * 32];
        #pragma unroll
        for (int j = 0; j < 16; ++j) qt[r][j] = p[j];
        qb[r] = Qbits[rowA + 4 * g + r];
    }
    const float f0 = fw[0], f1 = fw[1], f2 = fw[2];
    const float fm = fmaxf(f0, fmaxf(f1, f2));
    const float e0 = __expf(f0 - fm), e1 = __expf(f1 - fm), e2 = __expf(f2 - fm);
    const float wi = 1.f / (e0 + e1 + e2);
    const float w0 = e0 * wi, w1 = e1 * wi, w2 = e2 * wi;

    // ---- phase 1: raw scores -> LDS ----
    for (int i = 0; i < 16; ++i) {
        const int m0 = (w + 4 * i) * 16;
        const int mrow = b * 1024 + m0;
        const uint_t* ktp = (const uint_t*)&Kt_q[(size_t)(mrow + l15) * 32];
        uint_t kk[16];
        uint4 k0v = *(const uint4*)&ktp[0];
        uint4 k1v = *(const uint4*)&ktp[4];
        uint4 k2v = *(const uint4*)&ktp[8];
        uint4 k3v = *(const uint4*)&ktp[12];
        kk[0] = k0v.x; kk[1] = k0v.y; kk[2] = k0v.z; kk[3] = k0v.w;
        kk[4] = k1v.x; kk[5] = k1v.y; kk[6] = k1v.z; kk[7] = k1v.w;
        kk[8] = k2v.x; kk[9] = k2v.y; kk[10] = k2v.z; kk[11] = k2v.w;
        kk[12] = k3v.x; kk[13] = k3v.y; kk[14] = k3v.z; kk[15] = k3v.w;
        s16x8 krh = *(const s16x8*)&Krh[(size_t)(mrow + l15) * 32 + g * 8];
        s16x8 krm = *(const s16x8*)&Krm[(size_t)(mrow + l15) * 32 + g * 8];
        uint_t kb = Kbits[mrow + l15];
        int mk[4];
        #pragma unroll
        for (int r = 0; r < 4; ++r)
            mk[r] = mask[(size_t)(rowA + 4 * g + r) * 1024 + m0 + l15];

        f32x4 rc = f32x4{0.f, 0.f, 0.f, 0.f};
        rc = MFMA16(qrh, krh, rc);
        rc = MFMA16(qrh, krm, rc);
        rc = MFMA16(qrm, krh, rc);

        float trop[4];
        #pragma unroll
        for (int r = 0; r < 4; ++r) {
            unsigned a = pk_add(qt[r][0], kk[0]);
            #pragma unroll
            for (int j = 1; j < 16; ++j)
                a = pk_max(a, pk_add(qt[r][j], kk[j]));
            trop[r] = fmaxf(h2f((ushort_t)(a & 0xFFFF)), h2f((ushort_t)(a >> 16)));
        }
        #pragma unroll
        for (int r = 0; r < 4; ++r) {
            float cnt = (float)(32 - __popc(qb[r] ^ kb));
            float s = (w0 * cnt + w1 * trop[r] + w2 * rc[r]) * SCALE_F;
            *(float*)&S[4 * g + r][m0 + l15] = mk[r] ? s : -INFINITY;
        }
    }
    __syncthreads();

    // ---- phase 2: per-row max & sum (wave w -> rows 4w..4w+3) ----
    #pragma unroll
    for (int q = 0; q < 4; ++q) {
        const int row = 4 * w + q;
        float mx = -INFINITY;
        #pragma unroll
        for (int j = 0; j < 16; ++j)
            mx = fmaxf(mx, *(const float*)&S[row][lane + j * 64]);
        #pragma unroll
        for (int off = 32; off >= 1; off >>= 1) mx = fmaxf(mx, __shfl_xor(mx, off, 64));
        float sm = 0.f;
        #pragma unroll
        for (int j = 0; j < 16; ++j)
            sm += __expf(*(const float*)&S[row][lane + j * 64] - mx);
        #pragma unroll
        for (int off = 32; off >= 1; off >>= 1) sm += __shfl_xor(sm, off, 64);
        if (lane == 0) { rmaxS[row] = mx; rinvS[row] = 1.f / sm; }
    }
    __syncthreads();

    // ---- phase 3: normalize, write attn, repack P=hi|mid in place ----
    #pragma unroll
    for (int j = 0; j < 16; ++j) {
        const float mx = rmaxS[j], inv = rinvS[j];
        f4 s4 = *(const f4*)&S[j][t * 4];
        float p0 = __expf(s4.x - mx) * inv;
        float p1 = __expf(s4.y - mx) * inv;
        float p2 = __expf(s4.z - mx) * inv;
        float p3 = __expf(s4.w - mx) * inv;
        *(f4*)&attn[(size_t)(rowA + j) * 1024 + t * 4] = make_float4(p0, p1, p2, p3);
        ushort_t h0 = f2bf(p0), h1 = f2bf(p1), h2_ = f2bf(p2), h3 = f2bf(p3);
        uint4 pk;
        pk.x = (uint_t)h0 | ((uint_t)f2bf(p0 - bf2f(h0)) << 16);
        pk.y = (uint_t)h1 | ((uint_t)f2bf(p1 - bf2f(h1)) << 16);
        pk.z = (uint_t)h2_ | ((uint_t)f2bf(p2 - bf2f(h2_)) << 16);
        pk.w = (uint_t)h3 | ((uint_t)f2bf(p3 - bf2f(h3)) << 16);
        *(uint4*)&S[j][t * 4] = pk;
    }
    __syncthreads();

    // ---- phase 4: PV via MFMA, V codes straight from L2 ----
    const int hbase = w * 32;
    f32x4 acc[2];
    acc[0] = f32x4{0.f, 0.f, 0.f, 0.f};
    acc[1] = f32x4{0.f, 0.f, 0.f, 0.f};
    for (int mc = 0; mc < 32; ++mc) {
        const int m0 = mc * 32;
        uint4 ua = *(const uint4*)&S[l15][m0 + g * 8];
        uint4 ub = *(const uint4*)&S[l15][m0 + g * 8 + 4];
        u16x8 a1v, a2v;
        uint_t uu[8] = {ua.x, ua.y, ua.z, ua.w, ub.x, ub.y, ub.z, ub.w};
        #pragma unroll
        for (int j = 0; j < 8; ++j) {
            a1v[j] = (ushort_t)(uu[j] & 0xFFFFu);
            a2v[j] = (ushort_t)(uu[j] >> 16);
        }
        s16x8 a1 = (s16x8)a1v, a2 = (s16x8)a2v;
        #pragma unroll
        for (int cf = 0; cf < 2; ++cf) {
            const size_t vb = (size_t)(b * 128 + hbase + cf * 16 + l15) * 1024 + m0 + g * 8;
            s16x8 bh = *(const s16x8*)&VphT[vb];
            s16x8 bm = *(const s16x8*)&VpmT[vb];
            acc[cf] = MFMA16(a1, bh, acc[cf]);
            acc[cf] = MFMA16(a1, bm, acc[cf]);
            acc[cf] = MFMA16(a2, bh, acc[cf]);
        }
    }
    #pragma unroll
    for (int cf = 0; cf < 2; ++cf)
        #pragma unroll
        for (int r = 0; r < 4; ++r)
            out[(size_t)(rowA + 4 * g + r) * 128 + hbase + cf * 16 + l15] = acc[cf][r];
}

// ---------------- launch ----------------

extern "C" void kernel_launch(void* const* d_in, const int* in_sizes, int n_in,
                              void* d_out, int out_size, void* d_ws, size_t ws_size,
                              hipStream_t stream) {
    const float* Q   = (const float*)d_in[0];
    const float* K   = (const float*)d_in[1];
    const float* V   = (const float*)d_in[2];
    const float* Wqb = (const float*)d_in[3];
    const float* Wkb = (const float*)d_in[4];
    const float* Wqt = (const float*)d_in[5];
    const float* Wkt = (const float*)d_in[6];
    const float* Wqr = (const float*)d_in[7];
    const float* Wkr = (const float*)d_in[8];
    const float* Wv  = (const float*)d_in[9];
    const float* fw  = (const float*)d_in[10];
    const int*  mask = (const int*)d_in[11];

    ushort_t* wsu = (ushort_t*)d_ws;
    ushort_t* Wh   = wsu;              // [192][1024]
    ushort_t* Wm   = Wh + 196608;
    ushort_t* Wl3  = Wm + 196608;      // [64][1024] (conv_w writes; unused downstream)
    ushort_t* Wvh  = Wl3 + 65536;      // [128][1024]
    ushort_t* Wvm  = Wvh + 131072;
    ushort_t* Qt_q = Wvm + 131072;     // [8192][32] f16 trop codes
    ushort_t* Kt_q = Qt_q + 262144;
    ushort_t* Qrh  = Kt_q + 262144;    // [8192][32] bf16 hi/mid real codes
    ushort_t* Qrm  = Qrh + 262144;
    ushort_t* Krh  = Qrm + 262144;
    ushort_t* Krm  = Krh + 262144;
    ushort_t* VphT = Krm + 262144;     // [8*128][1024] bf16 hi/mid (transposed)
    ushort_t* VpmT = VphT + 1048576;
    uint_t* Qbits = (uint_t*)(VpmT + 1048576);
    uint_t* Kbits = Qbits + 8192;

    float* out  = (float*)d_out;       // [8192][128]
    float* attn = out + 1048576;       // [8192][1024]

    conv_w_kernel<<<40, 256, 0, stream>>>(Wqb, Wkb, Wqt, Wkt, Wqr, Wkr, Wv,
                                          Wh, Wm, Wl3, Wvh, Wvm);
    proj_qk_kernel<<<512, 256, 0, stream>>>(Q, K, Wh, Wm,
                                            Qt_q, Kt_q, Qrh, Qrm, Krh, Krm, Qbits, Kbits);
    proj_v_kernel<<<512, 256, 0, stream>>>(V, Wvh, Wvm, VphT, VpmT);
    fused_attn_kernel<<<512, 256, 0, stream>>>(Qt_q, Kt_q, Qrh, Qrm, Krh, Krm,
                                               Qbits, Kbits, VphT, VpmT,
                                               mask, fw, attn, out);
}